// Round 1
// baseline (910.265 us; speedup 1.0000x reference)
//
#include <hip/hip_runtime.h>
#include <hip/hip_bf16.h>
#include <math.h>

#define NB      2048
#define N_NUC   4
#define N_ELEC  16
#define N_PART  20
#define N_NODES (NB * N_PART)     // 40960
#define NE      307200
#define DD      64
#define KK      128
#define EMB     256
#define N_ESLOT (NB * N_ELEC)     // 32768

__device__ __forceinline__ float ssp_f(float x) {
    // softplus(x) - log(2), numerically stable
    float sp = fmaxf(x, 0.0f) + log1pf(expf(-fabsf(x)));
    return sp - 0.6931471805599453f;
}

// ---------------- kernel 1a: copy nuc rows into hx ----------------
__global__ __launch_bounds__(256) void hx_nuc_kernel(
    const float* __restrict__ nuc, float* __restrict__ hx)
{
    int idx = blockIdx.x * 256 + threadIdx.x;
    int total = NB * N_NUC * KK;      // 1,048,576
    for (; idx < total; idx += gridDim.x * 256) {
        int k  = idx & (KK - 1);
        int bp = idx >> 7;            // b*4 + p
        int b  = bp >> 2;
        int p  = bp & 3;
        hx[((size_t)(b * N_PART + p)) * KK + k] = nuc[idx];
    }
}

// ---------------- kernel 1b: hx elec rows = elec @ h_W + h_b ----------------
// block: 256 threads computes 32 rows x 128 cols
__global__ __launch_bounds__(256) void hx_elec_kernel(
    const float* __restrict__ elec, const float* __restrict__ h_W,
    const float* __restrict__ h_b, float* __restrict__ hx)
{
    __shared__ float se[32 * EMB];    // 32 KB
    int t = threadIdx.x;
    int row0 = blockIdx.x * 32;       // elec row base (0..32767)

    const float4* src4 = (const float4*)(elec + (size_t)row0 * EMB);
    float4* se4 = (float4*)se;
    for (int i = t; i < 32 * EMB / 4; i += 256) se4[i] = src4[i];
    __syncthreads();

    int c = t & 127;
    int h = t >> 7;                   // 0/1 -> rows h*16 .. h*16+15
    float acc[16];
#pragma unroll
    for (int r = 0; r < 16; ++r) acc[r] = 0.0f;

    for (int jq = 0; jq < EMB / 4; ++jq) {
        float g0 = h_W[(jq * 4 + 0) * KK + c];
        float g1 = h_W[(jq * 4 + 1) * KK + c];
        float g2 = h_W[(jq * 4 + 2) * KK + c];
        float g3 = h_W[(jq * 4 + 3) * KK + c];
#pragma unroll
        for (int r = 0; r < 16; ++r) {
            float4 ev = *(const float4*)&se[(h * 16 + r) * EMB + jq * 4];
            acc[r] = fmaf(ev.x, g0, acc[r]);
            acc[r] = fmaf(ev.y, g1, acc[r]);
            acc[r] = fmaf(ev.z, g2, acc[r]);
            acc[r] = fmaf(ev.w, g3, acc[r]);
        }
    }
    float hb = h_b[c];
#pragma unroll
    for (int r = 0; r < 16; ++r) {
        int erow = row0 + h * 16 + r;     // 0..32767
        int b = erow >> 4, i = erow & 15;
        int node = b * N_PART + N_NUC + i;
        hx[(size_t)node * KK + c] = acc[r] + hb;
    }
}

// ---------------- kernel 2: edge MLP + scatter (one pass per type) ----------------
// wave-per-edge; W1 (64x64), W2 (64x128) of the pass's type staged in LDS.
__global__ __launch_bounds__(256) void edge_pass_kernel(
    const float* __restrict__ dist, const int* __restrict__ e_type,
    const int* __restrict__ senders, const int* __restrict__ receivers,
    const float* __restrict__ W1, const float* __restrict__ b1,
    const float* __restrict__ W2, const float* __restrict__ b2,
    int want, int tslot,
    const float* __restrict__ hx, float* __restrict__ Z)
{
    __shared__ float sW1[DD * DD];   // 16 KB  [d][j]
    __shared__ float sW2[DD * KK];   // 32 KB  [j][k]
    __shared__ float sb1[DD];
    __shared__ float sb2[KK];

    int tid = threadIdx.x;
    for (int i = tid; i < DD * DD; i += 256) sW1[i] = W1[i];
    for (int i = tid; i < DD * KK; i += 256) sW2[i] = W2[i];
    if (tid < DD) sb1[tid] = b1[tid];
    if (tid < KK) sb2[tid] = b2[tid];
    __syncthreads();

    int lane = tid & 63;
    int wid = (blockIdx.x << 2) | (tid >> 6);
    int nw = gridDim.x << 2;

    for (int e = wid; e < NE; e += nw) {
        if (e_type[e] != want) continue;
        int r = receivers[e];
        int bb = r / N_PART;
        int p = r - bb * N_PART;
        if (p < N_NUC) continue;          // message to a nuclear node: dropped
        int slot = bb * N_ELEC + (p - N_NUC);

        float xd = dist[(size_t)e * DD + lane];

        // h1 = ssp(dist @ W1 + b1) ; lane owns column `lane`
        float acc = sb1[lane];
#pragma unroll
        for (int d = 0; d < DD; ++d) {
            float xv = __shfl(xd, d);
            acc = fmaf(xv, sW1[d * DD + lane], acc);
        }
        float h1 = ssp_f(acc);

        // we = h1 @ W2 + b2 ; lane owns columns lane, lane+64
        float a0 = sb2[lane];
        float a1 = sb2[lane + 64];
#pragma unroll
        for (int j = 0; j < DD; ++j) {
            float hv = __shfl(h1, j);
            a0 = fmaf(hv, sW2[j * KK + lane], a0);
            a1 = fmaf(hv, sW2[j * KK + lane + 64], a1);
        }

        int s = senders[e];
        float hx0 = hx[(size_t)s * KK + lane];
        float hx1 = hx[(size_t)s * KK + lane + 64];

        float* zr = Z + (size_t)slot * 384 + tslot * KK;
        atomicAdd(zr + lane, a0 * hx0);
        atomicAdd(zr + lane + 64, a1 * hx1);
    }
}

// ---------------- kernel 3: out = elec + Z @ [g_n;g_same;g_anti] + gb_sum ----------------
// block: 256 threads computes 32 rows x 256 cols
__global__ __launch_bounds__(256) void gout_kernel(
    const float* __restrict__ Z, const float* __restrict__ elec,
    const float* __restrict__ g_n_W, const float* __restrict__ g_n_b,
    const float* __restrict__ g_same_W, const float* __restrict__ g_same_b,
    const float* __restrict__ g_anti_W, const float* __restrict__ g_anti_b,
    float* __restrict__ out)
{
    __shared__ float sz[32 * 384];    // 48 KB
    int t = threadIdx.x;
    int row0 = blockIdx.x * 32;

    const float4* src4 = (const float4*)(Z + (size_t)row0 * 384);
    float4* sz4 = (float4*)sz;
    for (int i = t; i < 32 * 384 / 4; i += 256) sz4[i] = src4[i];
    __syncthreads();

    int c = t;                        // 0..255
    float acc[32];
#pragma unroll
    for (int r = 0; r < 32; ++r) acc[r] = 0.0f;

    const float* Gs[3] = { g_n_W, g_same_W, g_anti_W };
#pragma unroll 1
    for (int seg = 0; seg < 3; ++seg) {
        const float* G = Gs[seg];
        for (int jq = 0; jq < KK / 4; ++jq) {
            float g0 = G[(jq * 4 + 0) * EMB + c];
            float g1 = G[(jq * 4 + 1) * EMB + c];
            float g2 = G[(jq * 4 + 2) * EMB + c];
            float g3 = G[(jq * 4 + 3) * EMB + c];
#pragma unroll
            for (int r = 0; r < 32; ++r) {
                float4 zv = *(const float4*)&sz[r * 384 + seg * KK + jq * 4];
                acc[r] = fmaf(zv.x, g0, acc[r]);
                acc[r] = fmaf(zv.y, g1, acc[r]);
                acc[r] = fmaf(zv.z, g2, acc[r]);
                acc[r] = fmaf(zv.w, g3, acc[r]);
            }
        }
    }

    float gb = g_n_b[c] + g_same_b[c] + g_anti_b[c];
#pragma unroll
    for (int r = 0; r < 32; ++r) {
        size_t row = row0 + r;
        out[row * EMB + c] = elec[row * EMB + c] + acc[r] + gb;
    }
}

extern "C" void kernel_launch(void* const* d_in, const int* in_sizes, int n_in,
                              void* d_out, int out_size, void* d_ws, size_t ws_size,
                              hipStream_t stream) {
    const float* nuc       = (const float*)d_in[0];
    const float* elec      = (const float*)d_in[1];
    const float* dist      = (const float*)d_in[2];
    const int*   e_type    = (const int*)d_in[3];
    const int*   senders   = (const int*)d_in[4];
    const int*   receivers = (const int*)d_in[5];
    const float* w_same_W1 = (const float*)d_in[6];
    const float* w_same_b1 = (const float*)d_in[7];
    const float* w_same_W2 = (const float*)d_in[8];
    const float* w_same_b2 = (const float*)d_in[9];
    const float* w_anti_W1 = (const float*)d_in[10];
    const float* w_anti_b1 = (const float*)d_in[11];
    const float* w_anti_W2 = (const float*)d_in[12];
    const float* w_anti_b2 = (const float*)d_in[13];
    const float* w_n_W1    = (const float*)d_in[14];
    const float* w_n_b1    = (const float*)d_in[15];
    const float* w_n_W2    = (const float*)d_in[16];
    const float* w_n_b2    = (const float*)d_in[17];
    const float* h_W       = (const float*)d_in[18];
    const float* h_b       = (const float*)d_in[19];
    const float* g_same_W  = (const float*)d_in[20];
    const float* g_same_b  = (const float*)d_in[21];
    const float* g_anti_W  = (const float*)d_in[22];
    const float* g_anti_b  = (const float*)d_in[23];
    const float* g_n_W     = (const float*)d_in[24];
    const float* g_n_b     = (const float*)d_in[25];

    float* out = (float*)d_out;

    // workspace layout
    float* hx = (float*)d_ws;                                // N_NODES*K floats = 20 MB
    float* Z  = hx + (size_t)N_NODES * KK;                   // N_ESLOT*384 floats = 48 MB
    size_t zbytes = (size_t)N_ESLOT * 384 * sizeof(float);

    hipMemsetAsync(Z, 0, zbytes, stream);

    hx_nuc_kernel<<<1024, 256, 0, stream>>>(nuc, hx);
    hx_elec_kernel<<<N_ESLOT / 32, 256, 0, stream>>>(elec, h_W, h_b, hx);

    // e_type semantics: 1 -> w_n (slot 0), 3 -> w_same (slot 1), 4 -> w_anti (slot 2)
    edge_pass_kernel<<<2048, 256, 0, stream>>>(dist, e_type, senders, receivers,
        w_n_W1, w_n_b1, w_n_W2, w_n_b2, 1, 0, hx, Z);
    edge_pass_kernel<<<2048, 256, 0, stream>>>(dist, e_type, senders, receivers,
        w_same_W1, w_same_b1, w_same_W2, w_same_b2, 3, 1, hx, Z);
    edge_pass_kernel<<<2048, 256, 0, stream>>>(dist, e_type, senders, receivers,
        w_anti_W1, w_anti_b1, w_anti_W2, w_anti_b2, 4, 2, hx, Z);

    gout_kernel<<<N_ESLOT / 32, 256, 0, stream>>>(Z, elec,
        g_n_W, g_n_b, g_same_W, g_same_b, g_anti_W, g_anti_b, out);
}

// Round 2
// 692.907 us; speedup vs baseline: 1.3137x; 1.3137x over previous
//
#include <hip/hip_runtime.h>
#include <hip/hip_bf16.h>
#include <math.h>

#define NB      2048
#define N_NUC   4
#define N_ELEC  16
#define N_PART  20
#define N_NODES (NB * N_PART)     // 40960
#define NE      307200
#define NTILE   (NE / 16)         // 19200
#define DD      64
#define KK      128
#define EMB     256
#define N_ESLOT (NB * N_ELEC)     // 32768

typedef __attribute__((ext_vector_type(8))) short bf16x8;
typedef __attribute__((ext_vector_type(4))) float f32x4;

__device__ __forceinline__ float ssp_f(float x) {
    float sp = fmaxf(x, 0.0f) + log1pf(expf(-fabsf(x)));
    return sp - 0.6931471805599453f;
}

__device__ __forceinline__ unsigned short f2b(float f) {
    union { float f; unsigned int u; } v; v.f = f;
    unsigned int r = (v.u + 0x7fffu + ((v.u >> 16) & 1u)) >> 16;
    return (unsigned short)r;
}

// ---------------- kernel 1a: copy nuc rows into hx ----------------
__global__ __launch_bounds__(256) void hx_nuc_kernel(
    const float* __restrict__ nuc, float* __restrict__ hx)
{
    int idx = blockIdx.x * 256 + threadIdx.x;
    int total = NB * N_NUC * KK;
    for (; idx < total; idx += gridDim.x * 256) {
        int k  = idx & (KK - 1);
        int bp = idx >> 7;
        int b  = bp >> 2;
        int p  = bp & 3;
        hx[((size_t)(b * N_PART + p)) * KK + k] = nuc[idx];
    }
}

// ---------------- kernel 1b: hx elec rows = elec @ h_W + h_b ----------------
__global__ __launch_bounds__(256) void hx_elec_kernel(
    const float* __restrict__ elec, const float* __restrict__ h_W,
    const float* __restrict__ h_b, float* __restrict__ hx)
{
    __shared__ float se[32 * EMB];
    int t = threadIdx.x;
    int row0 = blockIdx.x * 32;

    const float4* src4 = (const float4*)(elec + (size_t)row0 * EMB);
    float4* se4 = (float4*)se;
    for (int i = t; i < 32 * EMB / 4; i += 256) se4[i] = src4[i];
    __syncthreads();

    int c = t & 127;
    int h = t >> 7;
    float acc[16];
#pragma unroll
    for (int r = 0; r < 16; ++r) acc[r] = 0.0f;

    for (int jq = 0; jq < EMB / 4; ++jq) {
        float g0 = h_W[(jq * 4 + 0) * KK + c];
        float g1 = h_W[(jq * 4 + 1) * KK + c];
        float g2 = h_W[(jq * 4 + 2) * KK + c];
        float g3 = h_W[(jq * 4 + 3) * KK + c];
#pragma unroll
        for (int r = 0; r < 16; ++r) {
            float4 ev = *(const float4*)&se[(h * 16 + r) * EMB + jq * 4];
            acc[r] = fmaf(ev.x, g0, acc[r]);
            acc[r] = fmaf(ev.y, g1, acc[r]);
            acc[r] = fmaf(ev.z, g2, acc[r]);
            acc[r] = fmaf(ev.w, g3, acc[r]);
        }
    }
    float hb = h_b[c];
#pragma unroll
    for (int r = 0; r < 16; ++r) {
        int erow = row0 + h * 16 + r;
        int b = erow >> 4, i = erow & 15;
        int node = b * N_PART + N_NUC + i;
        hx[(size_t)node * KK + c] = acc[r] + hb;
    }
}

// ---------------- kernel 2a: edge stage1 — h1 = ssp(dist @ W1_t + b1_t), bf16 ----------------
// wave per 16 edges; W1cat^T staged in LDS (192 rows x 72 bf16, conflict-free b128)
__global__ __launch_bounds__(256) void edge_stage1(
    const float* __restrict__ dist, const int* __restrict__ e_type,
    const float* __restrict__ w_n_W1,    const float* __restrict__ w_n_b1,
    const float* __restrict__ w_same_W1, const float* __restrict__ w_same_b1,
    const float* __restrict__ w_anti_W1, const float* __restrict__ w_anti_b1,
    unsigned short* __restrict__ h1g)
{
    __shared__ unsigned short sW1T[192 * 72];   // [n][d] = W1cat[d][n], n = t*64+c
    __shared__ float sb1[192];

    int tid = threadIdx.x;
    // stage W1^T (bf16) — n in [t*64, t*64+64), element [d][c] at d*64+c
    {
        for (int i = tid; i < 64 * 64; i += 256) {
            int n = i >> 6, d = i & 63;
            sW1T[(n      ) * 72 + d] = f2b(w_n_W1   [d * 64 + n]);
            sW1T[(n +  64) * 72 + d] = f2b(w_same_W1[d * 64 + n]);
            sW1T[(n + 128) * 72 + d] = f2b(w_anti_W1[d * 64 + n]);
        }
        for (int i = tid; i < 64; i += 256) {
            sb1[i]       = w_n_b1[i];
            sb1[i +  64] = w_same_b1[i];
            sb1[i + 128] = w_anti_b1[i];
        }
    }
    __syncthreads();

    int lane = tid & 63;
    int l15 = lane & 15, l4 = lane >> 4;
    int wid = blockIdx.x * 4 + (tid >> 6);
    int nw = gridDim.x * 4;

    for (int tile = wid; tile < NTILE; tile += nw) {
        int e0 = tile << 4;
        int myE = e0 + l15;
        int et = e_type[myE];
        int t = (et == 1) ? 0 : ((et == 3) ? 1 : 2);

        // A fragments: dist rows (fp32 -> bf16)
        bf16x8 a[2];
        const float* dp = dist + (size_t)myE * DD + l4 * 8;
#pragma unroll
        for (int ks = 0; ks < 2; ++ks) {
            float4 v0 = *(const float4*)(dp + ks * 32);
            float4 v1 = *(const float4*)(dp + ks * 32 + 4);
            bf16x8 av;
            av[0] = (short)f2b(v0.x); av[1] = (short)f2b(v0.y);
            av[2] = (short)f2b(v0.z); av[3] = (short)f2b(v0.w);
            av[4] = (short)f2b(v1.x); av[5] = (short)f2b(v1.y);
            av[6] = (short)f2b(v1.z); av[7] = (short)f2b(v1.w);
            a[ks] = av;
        }

        f32x4 acc[12];
#pragma unroll
        for (int nt = 0; nt < 12; ++nt) acc[nt] = (f32x4)(0.0f);

#pragma unroll
        for (int nt = 0; nt < 12; ++nt) {
#pragma unroll
            for (int ks = 0; ks < 2; ++ks) {
                bf16x8 b = *(const bf16x8*)&sW1T[(nt * 16 + l15) * 72 + ks * 32 + l4 * 8];
                acc[nt] = __builtin_amdgcn_mfma_f32_16x16x32_bf16(a[ks], b, acc[nt], 0, 0, 0);
            }
        }

        // select by row type, add bias, ssp, store bf16
#pragma unroll
        for (int r = 0; r < 4; ++r) {
            int m = l4 * 4 + r;
            int tr = __shfl(t, m);
            unsigned short* op = h1g + (size_t)(e0 + m) * DD + l15;
#pragma unroll
            for (int q = 0; q < 4; ++q) {
                float vn = acc[q][r];
                float vs = acc[4 + q][r];
                float va = acc[8 + q][r];
                float v = (tr == 0) ? vn : ((tr == 1) ? vs : va);
                v += sb1[tr * 64 + q * 16 + l15];
                v = ssp_f(v);
                op[q * 16] = f2b(v);
            }
        }
    }
}

// ---------------- kernel 2b: edge stage2 — we = h1 @ W2_t + b2_t; scatter we*hx[s] ----------------
__global__ __launch_bounds__(256) void edge_stage2(
    const unsigned short* __restrict__ h1g, const int* __restrict__ e_type,
    const int* __restrict__ senders, const int* __restrict__ receivers,
    const float* __restrict__ w_n_W2,    const float* __restrict__ w_n_b2,
    const float* __restrict__ w_same_W2, const float* __restrict__ w_same_b2,
    const float* __restrict__ w_anti_W2, const float* __restrict__ w_anti_b2,
    const float* __restrict__ hx, float* __restrict__ Z)
{
    __shared__ unsigned short sW2T[384 * 72];   // [n][j] = W2cat[j][n], n = t*128+c
    __shared__ float sb2[384];

    int tid = threadIdx.x;
    {
        for (int i = tid; i < 128 * 64; i += 256) {
            int n = i >> 6, j = i & 63;   // n in [0,128)
            sW2T[(n      ) * 72 + j] = f2b(w_n_W2   [j * KK + n]);
            sW2T[(n + 128) * 72 + j] = f2b(w_same_W2[j * KK + n]);
            sW2T[(n + 256) * 72 + j] = f2b(w_anti_W2[j * KK + n]);
        }
        for (int i = tid; i < 128; i += 256) {
            sb2[i]       = w_n_b2[i];
            sb2[i + 128] = w_same_b2[i];
            sb2[i + 256] = w_anti_b2[i];
        }
    }
    __syncthreads();

    int lane = tid & 63;
    int l15 = lane & 15, l4 = lane >> 4;
    int wid = blockIdx.x * 4 + (tid >> 6);
    int nw = gridDim.x * 4;

    for (int tile = wid; tile < NTILE; tile += nw) {
        int e0 = tile << 4;
        int myE = e0 + l15;
        int et = e_type[myE];
        int t = (et == 1) ? 0 : ((et == 3) ? 1 : 2);
        int rcv = receivers[myE];
        int bb = rcv / N_PART;
        int p = rcv - bb * N_PART;
        int ok = (p >= N_NUC) ? 1 : 0;
        int slot = bb * N_ELEC + p - N_NUC;
        int snd = senders[myE];

        // A fragments straight from bf16 h1
        const unsigned short* hp = h1g + (size_t)myE * DD + l4 * 8;
        bf16x8 a[2];
        a[0] = *(const bf16x8*)hp;
        a[1] = *(const bf16x8*)(hp + 32);

        f32x4 acc[24];
#pragma unroll
        for (int nt = 0; nt < 24; ++nt) acc[nt] = (f32x4)(0.0f);

#pragma unroll
        for (int nt = 0; nt < 24; ++nt) {
#pragma unroll
            for (int ks = 0; ks < 2; ++ks) {
                bf16x8 b = *(const bf16x8*)&sW2T[(nt * 16 + l15) * 72 + ks * 32 + l4 * 8];
                acc[nt] = __builtin_amdgcn_mfma_f32_16x16x32_bf16(a[ks], b, acc[nt], 0, 0, 0);
            }
        }

        // per output row: select type block, add bias, multiply hx[sender], scatter
#pragma unroll
        for (int r = 0; r < 4; ++r) {
            int m = l4 * 4 + r;
            int tr  = __shfl(t, m);
            int okr = __shfl(ok, m);
            int slr = __shfl(slot, m);
            int sdr = __shfl(snd, m);
            float* zrow = Z + (size_t)slr * 384 + tr * KK + l15;
            const float* hrow = hx + (size_t)sdr * KK + l15;
#pragma unroll
            for (int j = 0; j < 8; ++j) {
                float wn = acc[j][r];
                float ws = acc[8 + j][r];
                float wa = acc[16 + j][r];
                float w = (tr == 0) ? wn : ((tr == 1) ? ws : wa);
                w += sb2[tr * KK + j * 16 + l15];
                float hv = hrow[j * 16];
                if (okr) atomicAdd(&zrow[j * 16], w * hv);
            }
        }
    }
}

// ---------------- kernel 3: out = elec + Z @ [g_n;g_same;g_anti] + gb ----------------
__global__ __launch_bounds__(256) void gout_kernel(
    const float* __restrict__ Z, const float* __restrict__ elec,
    const float* __restrict__ g_n_W, const float* __restrict__ g_n_b,
    const float* __restrict__ g_same_W, const float* __restrict__ g_same_b,
    const float* __restrict__ g_anti_W, const float* __restrict__ g_anti_b,
    float* __restrict__ out)
{
    __shared__ float sz[32 * 384];
    int t = threadIdx.x;
    int row0 = blockIdx.x * 32;

    const float4* src4 = (const float4*)(Z + (size_t)row0 * 384);
    float4* sz4 = (float4*)sz;
    for (int i = t; i < 32 * 384 / 4; i += 256) sz4[i] = src4[i];
    __syncthreads();

    int c = t;
    float acc[32];
#pragma unroll
    for (int r = 0; r < 32; ++r) acc[r] = 0.0f;

    const float* Gs[3] = { g_n_W, g_same_W, g_anti_W };
#pragma unroll 1
    for (int seg = 0; seg < 3; ++seg) {
        const float* G = Gs[seg];
        for (int jq = 0; jq < KK / 4; ++jq) {
            float g0 = G[(jq * 4 + 0) * EMB + c];
            float g1 = G[(jq * 4 + 1) * EMB + c];
            float g2 = G[(jq * 4 + 2) * EMB + c];
            float g3 = G[(jq * 4 + 3) * EMB + c];
#pragma unroll
            for (int r = 0; r < 32; ++r) {
                float4 zv = *(const float4*)&sz[r * 384 + seg * KK + jq * 4];
                acc[r] = fmaf(zv.x, g0, acc[r]);
                acc[r] = fmaf(zv.y, g1, acc[r]);
                acc[r] = fmaf(zv.z, g2, acc[r]);
                acc[r] = fmaf(zv.w, g3, acc[r]);
            }
        }
    }

    float gb = g_n_b[c] + g_same_b[c] + g_anti_b[c];
#pragma unroll
    for (int r = 0; r < 32; ++r) {
        size_t row = row0 + r;
        out[row * EMB + c] = elec[row * EMB + c] + acc[r] + gb;
    }
}

extern "C" void kernel_launch(void* const* d_in, const int* in_sizes, int n_in,
                              void* d_out, int out_size, void* d_ws, size_t ws_size,
                              hipStream_t stream) {
    const float* nuc       = (const float*)d_in[0];
    const float* elec      = (const float*)d_in[1];
    const float* dist      = (const float*)d_in[2];
    const int*   e_type    = (const int*)d_in[3];
    const int*   senders   = (const int*)d_in[4];
    const int*   receivers = (const int*)d_in[5];
    const float* w_same_W1 = (const float*)d_in[6];
    const float* w_same_b1 = (const float*)d_in[7];
    const float* w_same_W2 = (const float*)d_in[8];
    const float* w_same_b2 = (const float*)d_in[9];
    const float* w_anti_W1 = (const float*)d_in[10];
    const float* w_anti_b1 = (const float*)d_in[11];
    const float* w_anti_W2 = (const float*)d_in[12];
    const float* w_anti_b2 = (const float*)d_in[13];
    const float* w_n_W1    = (const float*)d_in[14];
    const float* w_n_b1    = (const float*)d_in[15];
    const float* w_n_W2    = (const float*)d_in[16];
    const float* w_n_b2    = (const float*)d_in[17];
    const float* h_W       = (const float*)d_in[18];
    const float* h_b       = (const float*)d_in[19];
    const float* g_same_W  = (const float*)d_in[20];
    const float* g_same_b  = (const float*)d_in[21];
    const float* g_anti_W  = (const float*)d_in[22];
    const float* g_anti_b  = (const float*)d_in[23];
    const float* g_n_W     = (const float*)d_in[24];
    const float* g_n_b     = (const float*)d_in[25];

    float* out = (float*)d_out;

    // workspace layout
    float* hx = (float*)d_ws;                               // 20 MB
    float* Z  = hx + (size_t)N_NODES * KK;                  // 48 MB
    unsigned short* h1g = (unsigned short*)(Z + (size_t)N_ESLOT * 384);  // 39 MB
    size_t zbytes = (size_t)N_ESLOT * 384 * sizeof(float);

    hipMemsetAsync(Z, 0, zbytes, stream);

    hx_nuc_kernel<<<1024, 256, 0, stream>>>(nuc, hx);
    hx_elec_kernel<<<N_ESLOT / 32, 256, 0, stream>>>(elec, h_W, h_b, hx);

    edge_stage1<<<2400, 256, 0, stream>>>(dist, e_type,
        w_n_W1, w_n_b1, w_same_W1, w_same_b1, w_anti_W1, w_anti_b1, h1g);

    edge_stage2<<<2048, 256, 0, stream>>>(h1g, e_type, senders, receivers,
        w_n_W2, w_n_b2, w_same_W2, w_same_b2, w_anti_W2, w_anti_b2, hx, Z);

    gout_kernel<<<N_ESLOT / 32, 256, 0, stream>>>(Z, elec,
        g_n_W, g_n_b, g_same_W, g_same_b, g_anti_W, g_anti_b, out);
}

// Round 3
// 431.730 us; speedup vs baseline: 2.1084x; 1.6050x over previous
//
#include <hip/hip_runtime.h>
#include <hip/hip_bf16.h>
#include <math.h>

#define NB      2048
#define N_NUC   4
#define N_ELEC  16
#define N_PART  20
#define N_NODES (NB * N_PART)     // 40960
#define NE      307200
#define NTILE   (NE / 16)         // 19200
#define DD      64
#define KK      128
#define EMB     256
#define N_ESLOT (NB * N_ELEC)     // 32768
#define NKEY    (N_ESLOT * 3)     // 98304

typedef __attribute__((ext_vector_type(8))) short bf16x8;
typedef __attribute__((ext_vector_type(4))) float f32x4;
typedef unsigned short ushort_t;

__device__ __forceinline__ float ssp_f(float x) {
    float sp = fmaxf(x, 0.0f) + log1pf(expf(-fabsf(x)));
    return sp - 0.6931471805599453f;
}
__device__ __forceinline__ unsigned short f2b(float f) {
    union { float f; unsigned int u; } v; v.f = f;
    unsigned int r = (v.u + 0x7fffu + ((v.u >> 16) & 1u)) >> 16;
    return (unsigned short)r;
}
__device__ __forceinline__ float b2f(unsigned short u) {
    union { unsigned int u; float f; } v; v.u = ((unsigned int)u) << 16;
    return v.f;
}

// ================= prep: pack weights into MFMA-fragment layout (bf16) =================
// chunk c holds 16B = 8 bf16 elems for (tile nt, k-slice ks, lane): elem j = W[k][n],
// k = ks*32 + (lane>>4)*8 + j, n = nt*16 + (lane&15).
// W1pack: 1536 chunks | W2pack: 3072 | HWT: 4096 | GT: 12288 | then b1cat(192), b2cat(384) fp32
__global__ __launch_bounds__(256) void prep_kernel(
    const float* __restrict__ w_n_W1, const float* __restrict__ w_same_W1, const float* __restrict__ w_anti_W1,
    const float* __restrict__ w_n_W2, const float* __restrict__ w_same_W2, const float* __restrict__ w_anti_W2,
    const float* __restrict__ h_W,
    const float* __restrict__ g_n_W, const float* __restrict__ g_same_W, const float* __restrict__ g_anti_W,
    const float* __restrict__ w_n_b1, const float* __restrict__ w_same_b1, const float* __restrict__ w_anti_b1,
    const float* __restrict__ w_n_b2, const float* __restrict__ w_same_b2, const float* __restrict__ w_anti_b2,
    ushort_t* __restrict__ pack, float* __restrict__ b1cat, float* __restrict__ b2cat)
{
    int c = blockIdx.x * 256 + threadIdx.x;
    if (c < 1536) {                       // W1pack: nt 0..11 (n=192), ks 0..1 (k=64)
        int lane = c & 63, ks = (c >> 6) & 1, nt = c >> 7;
        ushort_t* dst = pack + (size_t)c * 8;
#pragma unroll
        for (int j = 0; j < 8; ++j) {
            int k = ks * 32 + ((lane >> 4) << 3) + j;
            int n = nt * 16 + (lane & 15);
            float v = (n < 64) ? w_n_W1[k * 64 + n]
                   : (n < 128) ? w_same_W1[k * 64 + n - 64]
                               : w_anti_W1[k * 64 + n - 128];
            dst[j] = f2b(v);
        }
    } else if (c < 1536 + 3072) {         // W2pack: nt 0..23 (n=384), ks 0..1 (k=64)
        int c2 = c - 1536;
        int lane = c2 & 63, ks = (c2 >> 6) & 1, nt = c2 >> 7;
        ushort_t* dst = pack + (size_t)c * 8;
#pragma unroll
        for (int j = 0; j < 8; ++j) {
            int k = ks * 32 + ((lane >> 4) << 3) + j;
            int n = nt * 16 + (lane & 15);
            float v = (n < 128) ? w_n_W2[k * KK + n]
                   : (n < 256) ? w_same_W2[k * KK + n - 128]
                               : w_anti_W2[k * KK + n - 256];
            dst[j] = f2b(v);
        }
    } else if (c < 1536 + 3072 + 4096) {  // HWT: nt 0..7 (n=128), ks 0..7 (k=256)
        int c3 = c - (1536 + 3072);
        int lane = c3 & 63, ks = (c3 >> 6) & 7, nt = c3 >> 9;
        ushort_t* dst = pack + (size_t)c * 8;
#pragma unroll
        for (int j = 0; j < 8; ++j) {
            int k = ks * 32 + ((lane >> 4) << 3) + j;
            int n = nt * 16 + (lane & 15);
            dst[j] = f2b(h_W[k * KK + n]);
        }
    } else if (c < 20992) {               // GT: nt 0..15 (n=256), ks 0..11 (k=384)
        int c4 = c - (1536 + 3072 + 4096);
        int lane = c4 & 63, ks = (c4 >> 6) % 12, nt = c4 / 768;
        ushort_t* dst = pack + (size_t)c * 8;
#pragma unroll
        for (int j = 0; j < 8; ++j) {
            int k = ks * 32 + ((lane >> 4) << 3) + j;
            int n = nt * 16 + (lane & 15);
            float v = (k < 128) ? g_n_W[k * EMB + n]
                   : (k < 256) ? g_same_W[(k - 128) * EMB + n]
                               : g_anti_W[(k - 256) * EMB + n];
            dst[j] = f2b(v);
        }
    } else if (c < 20992 + 192) {
        int i = c - 20992;
        b1cat[i] = (i < 64) ? w_n_b1[i] : (i < 128) ? w_same_b1[i - 64] : w_anti_b1[i - 128];
    } else if (c < 20992 + 192 + 384) {
        int i = c - 20992 - 192;
        b2cat[i] = (i < 128) ? w_n_b2[i] : (i < 256) ? w_same_b2[i - 128] : w_anti_b2[i - 256];
    }
}

// ================= hx build =================
__global__ __launch_bounds__(256) void hx_nuc_b(
    const float* __restrict__ nuc, ushort_t* __restrict__ hxb)
{
    int i = blockIdx.x * 256 + threadIdx.x;       // float4 index, 262144 total
    float4 v = ((const float4*)nuc)[i];
    int e = i << 2;
    int k = e & 127;
    int bp = e >> 7;
    int node = (bp >> 2) * N_PART + (bp & 3);
    union { unsigned int u[2]; } o;
    o.u[0] = (unsigned int)f2b(v.x) | ((unsigned int)f2b(v.y) << 16);
    o.u[1] = (unsigned int)f2b(v.z) | ((unsigned int)f2b(v.w) << 16);
    *(uint2*)(hxb + (size_t)node * KK + k) = *(uint2*)&o;
}

// hx elec rows via MFMA: M=32768, N=128, K=256. Block = 4 waves, 64 rows.
__global__ __launch_bounds__(256) void hx_elec_mfma(
    const float* __restrict__ elec, const ushort_t* __restrict__ HWT,
    const float* __restrict__ h_b, ushort_t* __restrict__ hxb)
{
    int tid = threadIdx.x;
    int lane = tid & 63;
    int l15 = lane & 15, l4 = lane >> 4;
    int row0 = blockIdx.x * 64 + (tid >> 6) * 16;

    bf16x8 a[8];
    const float* ep = elec + (size_t)(row0 + l15) * EMB + l4 * 8;
#pragma unroll
    for (int ks = 0; ks < 8; ++ks) {
        float4 v0 = *(const float4*)(ep + ks * 32);
        float4 v1 = *(const float4*)(ep + ks * 32 + 4);
        bf16x8 av;
        av[0] = (short)f2b(v0.x); av[1] = (short)f2b(v0.y);
        av[2] = (short)f2b(v0.z); av[3] = (short)f2b(v0.w);
        av[4] = (short)f2b(v1.x); av[5] = (short)f2b(v1.y);
        av[6] = (short)f2b(v1.z); av[7] = (short)f2b(v1.w);
        a[ks] = av;
    }

    f32x4 acc[8];
#pragma unroll
    for (int nt = 0; nt < 8; ++nt) acc[nt] = (f32x4)(0.0f);
#pragma unroll
    for (int nt = 0; nt < 8; ++nt) {
#pragma unroll
        for (int ks = 0; ks < 8; ++ks) {
            bf16x8 b = *(const bf16x8*)(HWT + ((size_t)(nt * 8 + ks) * 64 + lane) * 8);
            acc[nt] = __builtin_amdgcn_mfma_f32_16x16x32_bf16(a[ks], b, acc[nt], 0, 0, 0);
        }
    }
#pragma unroll
    for (int nt = 0; nt < 8; ++nt) {
        int n = nt * 16 + l15;
        float hb = h_b[n];
#pragma unroll
        for (int r = 0; r < 4; ++r) {
            int erow = row0 + l4 * 4 + r;
            int node = (erow >> 4) * N_PART + N_NUC + (erow & 15);
            hxb[(size_t)node * KK + n] = f2b(acc[nt][r] + hb);
        }
    }
}

// ================= sort by (slot, type) =================
__global__ __launch_bounds__(256) void hist_kernel(
    const int* __restrict__ receivers, const int* __restrict__ e_type,
    int* __restrict__ cnt, int* __restrict__ rank)
{
    int e = blockIdx.x * 256 + threadIdx.x;
    if (e >= NE) return;
    int r = receivers[e];
    int bb = r / N_PART;
    int p = r - bb * N_PART;
    if (p >= N_NUC) {
        int et = e_type[e];
        int t = (et == 1) ? 0 : ((et == 3) ? 1 : 2);
        int key = (bb * N_ELEC + p - N_NUC) * 3 + t;
        rank[e] = atomicAdd(&cnt[key], 1);
    } else {
        rank[e] = -1;
    }
}

__global__ __launch_bounds__(1024) void scan_kernel(int* __restrict__ cnt)
{
    __shared__ int part[1024];
    int t = threadIdx.x;
    int base = t * (NKEY / 1024);   // 96 each
    int s = 0;
    for (int i = 0; i < NKEY / 1024; ++i) s += cnt[base + i];
    part[t] = s;
    __syncthreads();
    for (int off = 1; off < 1024; off <<= 1) {
        int add = (t >= off) ? part[t - off] : 0;
        __syncthreads();
        part[t] += add;
        __syncthreads();
    }
    int run = part[t] - s;          // exclusive prefix
    for (int i = 0; i < NKEY / 1024; ++i) {
        int c = cnt[base + i];
        cnt[base + i] = run;
        run += c;
    }
    if (t == 1023) cnt[NKEY] = run;
}

__global__ __launch_bounds__(256) void scatter_kernel(
    const int* __restrict__ receivers, const int* __restrict__ e_type,
    const int* __restrict__ cnt, const int* __restrict__ rank, int* __restrict__ eidx)
{
    int e = blockIdx.x * 256 + threadIdx.x;
    if (e >= NE) return;
    int rk = rank[e];
    if (rk < 0) return;
    int r = receivers[e];
    int bb = r / N_PART;
    int p = r - bb * N_PART;
    int et = e_type[e];
    int t = (et == 1) ? 0 : ((et == 3) ? 1 : 2);
    int key = (bb * N_ELEC + p - N_NUC) * 3 + t;
    eidx[cnt[key] + rk] = e;
}

// ================= edge stage1: h1 = ssp(dist @ W1_t + b1_t) -> buf[:,0:64] bf16 =================
__global__ __launch_bounds__(256) void edge_stage1(
    const float* __restrict__ dist, const int* __restrict__ e_type,
    const uint4* __restrict__ W1pack, const float* __restrict__ b1cat,
    ushort_t* __restrict__ buf)
{
    __shared__ uint4 sW1[1536];        // 24576 B, frag-packed
    __shared__ float sb1[192];
    int tid = threadIdx.x;
    for (int i = tid; i < 1536; i += 256) sW1[i] = W1pack[i];
    if (tid < 192) sb1[tid] = b1cat[tid];
    __syncthreads();

    int lane = tid & 63;
    int l15 = lane & 15, l4 = lane >> 4;
    int wid = blockIdx.x * 4 + (tid >> 6);
    int nw = gridDim.x * 4;

    for (int tile = wid; tile < NTILE; tile += nw) {
        int e0 = tile << 4;
        int myE = e0 + l15;
        int et = e_type[myE];
        int t = (et == 1) ? 0 : ((et == 3) ? 1 : 2);

        bf16x8 a[2];
        const float* dp = dist + (size_t)myE * DD + l4 * 8;
#pragma unroll
        for (int ks = 0; ks < 2; ++ks) {
            float4 v0 = *(const float4*)(dp + ks * 32);
            float4 v1 = *(const float4*)(dp + ks * 32 + 4);
            bf16x8 av;
            av[0] = (short)f2b(v0.x); av[1] = (short)f2b(v0.y);
            av[2] = (short)f2b(v0.z); av[3] = (short)f2b(v0.w);
            av[4] = (short)f2b(v1.x); av[5] = (short)f2b(v1.y);
            av[6] = (short)f2b(v1.z); av[7] = (short)f2b(v1.w);
            a[ks] = av;
        }

        f32x4 acc[12];
#pragma unroll
        for (int nt = 0; nt < 12; ++nt) acc[nt] = (f32x4)(0.0f);
#pragma unroll
        for (int nt = 0; nt < 12; ++nt) {
#pragma unroll
            for (int ks = 0; ks < 2; ++ks) {
                bf16x8 b = *(const bf16x8*)&sW1[(nt * 2 + ks) * 64 + lane];
                acc[nt] = __builtin_amdgcn_mfma_f32_16x16x32_bf16(a[ks], b, acc[nt], 0, 0, 0);
            }
        }

#pragma unroll
        for (int r = 0; r < 4; ++r) {
            int m = l4 * 4 + r;
            int tr = __shfl(t, m);
            ushort_t* op = buf + (size_t)(e0 + m) * KK + l15;
#pragma unroll
            for (int q = 0; q < 4; ++q) {
                float vn = acc[q][r];
                float vs = acc[4 + q][r];
                float va = acc[8 + q][r];
                float v = (tr == 0) ? vn : ((tr == 1) ? vs : va);
                v += sb1[tr * 64 + q * 16 + l15];
                op[q * 16] = f2b(ssp_f(v));
            }
        }
    }
}

// ================= edge stage2: weh = (h1 @ W2_t + b2_t) * hx[sender] -> buf[:,0:128] bf16 =================
__global__ __launch_bounds__(256) void edge_stage2(
    const int* __restrict__ e_type, const int* __restrict__ senders,
    const uint4* __restrict__ W2pack, const float* __restrict__ b2cat,
    const ushort_t* __restrict__ hxb, ushort_t* __restrict__ buf)
{
    __shared__ uint4 sW2[3072];        // 49152 B
    __shared__ float sb2[384];
    int tid = threadIdx.x;
    for (int i = tid; i < 3072; i += 256) sW2[i] = W2pack[i];
    for (int i = tid; i < 384; i += 256) sb2[i] = b2cat[i];
    __syncthreads();

    int lane = tid & 63;
    int l15 = lane & 15, l4 = lane >> 4;
    int wid = blockIdx.x * 4 + (tid >> 6);
    int nw = gridDim.x * 4;

    for (int tile = wid; tile < NTILE; tile += nw) {
        int e0 = tile << 4;
        int myE = e0 + l15;
        int et = e_type[myE];
        int t = (et == 1) ? 0 : ((et == 3) ? 1 : 2);
        int snd = senders[myE];

        const ushort_t* hp = buf + (size_t)myE * KK;
        bf16x8 a[2];
        a[0] = *(const bf16x8*)(hp + l4 * 8);
        a[1] = *(const bf16x8*)(hp + 32 + l4 * 8);

        f32x4 acc[24];
#pragma unroll
        for (int nt = 0; nt < 24; ++nt) acc[nt] = (f32x4)(0.0f);
#pragma unroll
        for (int nt = 0; nt < 24; ++nt) {
#pragma unroll
            for (int ks = 0; ks < 2; ++ks) {
                bf16x8 b = *(const bf16x8*)&sW2[(nt * 2 + ks) * 64 + lane];
                acc[nt] = __builtin_amdgcn_mfma_f32_16x16x32_bf16(a[ks], b, acc[nt], 0, 0, 0);
            }
        }

#pragma unroll
        for (int r = 0; r < 4; ++r) {
            int m = l4 * 4 + r;
            int tr  = __shfl(t, m);
            int sdr = __shfl(snd, m);
            const ushort_t* hrow = hxb + (size_t)sdr * KK + l15;
            ushort_t* op = buf + (size_t)(e0 + m) * KK + l15;
#pragma unroll
            for (int j = 0; j < 8; ++j) {
                float wn = acc[j][r];
                float ws = acc[8 + j][r];
                float wa = acc[16 + j][r];
                float w = (tr == 0) ? wn : ((tr == 1) ? ws : wa);
                w += sb2[tr * KK + j * 16 + l15];
                float hv = b2f(hrow[j * 16]);
                op[j * 16] = f2b(w * hv);
            }
        }
    }
}

// ================= zgather: Z[slot][3*128] = sum of bucketed weh rows (no atomics) =================
__global__ __launch_bounds__(256) void zgather_kernel(
    const int* __restrict__ cnt, const int* __restrict__ eidx,
    const ushort_t* __restrict__ buf, ushort_t* __restrict__ Zb)
{
    int tid = threadIdx.x;
    int lane = tid & 63;
    int wid = blockIdx.x * 4 + (tid >> 6);
    int nw = gridDim.x * 4;

    for (int slot = wid; slot < N_ESLOT; slot += nw) {
        float acc[6] = {0, 0, 0, 0, 0, 0};
        int s0 = cnt[slot * 3];
        int s1 = cnt[slot * 3 + 1];
        int s2 = cnt[slot * 3 + 2];
        int s3 = cnt[slot * 3 + 3];
#pragma unroll 3
        for (int t = 0; t < 3; ++t) {
            int lo = (t == 0) ? s0 : (t == 1) ? s1 : s2;
            int hi = (t == 0) ? s1 : (t == 1) ? s2 : s3;
            for (int i = lo; i < hi; ++i) {
                int e = eidx[i];
                unsigned int v = *(const unsigned int*)(buf + (size_t)e * KK + 2 * lane);
                acc[t * 2]     += b2f((unsigned short)(v & 0xffff));
                acc[t * 2 + 1] += b2f((unsigned short)(v >> 16));
            }
        }
        ushort_t* zp = Zb + (size_t)slot * 384;
#pragma unroll 3
        for (int t = 0; t < 3; ++t) {
            unsigned int o = (unsigned int)f2b(acc[t * 2]) | ((unsigned int)f2b(acc[t * 2 + 1]) << 16);
            *(unsigned int*)(zp + t * KK + 2 * lane) = o;
        }
    }
}

// ================= gout: out = elec + Zb @ GT + gb (MFMA, M=32768,N=256,K=384) =================
__global__ __launch_bounds__(256) void gout_mfma(
    const ushort_t* __restrict__ Zb, const float* __restrict__ elec,
    const ushort_t* __restrict__ GT,
    const float* __restrict__ g_n_b, const float* __restrict__ g_same_b, const float* __restrict__ g_anti_b,
    float* __restrict__ out)
{
    int tid = threadIdx.x;
    int lane = tid & 63;
    int l15 = lane & 15, l4 = lane >> 4;
    int row0 = blockIdx.x * 64 + (tid >> 6) * 16;

    bf16x8 a[12];
    const ushort_t* zp = Zb + (size_t)(row0 + l15) * 384 + l4 * 8;
#pragma unroll
    for (int ks = 0; ks < 12; ++ks)
        a[ks] = *(const bf16x8*)(zp + ks * 32);

    f32x4 acc[16];
#pragma unroll
    for (int nt = 0; nt < 16; ++nt) acc[nt] = (f32x4)(0.0f);
#pragma unroll
    for (int nt = 0; nt < 16; ++nt) {
#pragma unroll
        for (int ks = 0; ks < 12; ++ks) {
            bf16x8 b = *(const bf16x8*)(GT + ((size_t)(nt * 12 + ks) * 64 + lane) * 8);
            acc[nt] = __builtin_amdgcn_mfma_f32_16x16x32_bf16(a[ks], b, acc[nt], 0, 0, 0);
        }
    }

#pragma unroll
    for (int nt = 0; nt < 16; ++nt) {
        int n = nt * 16 + l15;
        float gb = g_n_b[n] + g_same_b[n] + g_anti_b[n];
#pragma unroll
        for (int r = 0; r < 4; ++r) {
            size_t row = row0 + l4 * 4 + r;
            out[row * EMB + n] = elec[row * EMB + n] + acc[nt][r] + gb;
        }
    }
}

extern "C" void kernel_launch(void* const* d_in, const int* in_sizes, int n_in,
                              void* d_out, int out_size, void* d_ws, size_t ws_size,
                              hipStream_t stream) {
    const float* nuc       = (const float*)d_in[0];
    const float* elec      = (const float*)d_in[1];
    const float* dist      = (const float*)d_in[2];
    const int*   e_type    = (const int*)d_in[3];
    const int*   senders   = (const int*)d_in[4];
    const int*   receivers = (const int*)d_in[5];
    const float* w_same_W1 = (const float*)d_in[6];
    const float* w_same_b1 = (const float*)d_in[7];
    const float* w_same_W2 = (const float*)d_in[8];
    const float* w_same_b2 = (const float*)d_in[9];
    const float* w_anti_W1 = (const float*)d_in[10];
    const float* w_anti_b1 = (const float*)d_in[11];
    const float* w_anti_W2 = (const float*)d_in[12];
    const float* w_anti_b2 = (const float*)d_in[13];
    const float* w_n_W1    = (const float*)d_in[14];
    const float* w_n_b1    = (const float*)d_in[15];
    const float* w_n_W2    = (const float*)d_in[16];
    const float* w_n_b2    = (const float*)d_in[17];
    const float* h_W       = (const float*)d_in[18];
    const float* h_b       = (const float*)d_in[19];
    const float* g_same_W  = (const float*)d_in[20];
    const float* g_same_b  = (const float*)d_in[21];
    const float* g_anti_W  = (const float*)d_in[22];
    const float* g_anti_b  = (const float*)d_in[23];
    const float* g_n_W     = (const float*)d_in[24];
    const float* g_n_b     = (const float*)d_in[25];

    float* out = (float*)d_out;

    // ---- workspace layout (bytes) ----
    char* w = (char*)d_ws;
    ushort_t* pack   = (ushort_t*)w;                       // 20992*16 = 335872
    size_t off = 20992 * 16;
    float* b1cat = (float*)(w + off);  off += 192 * 4;
    float* b2cat = (float*)(w + off);  off += 384 * 4;
    off = (off + 255) & ~(size_t)255;
    ushort_t* hxb = (ushort_t*)(w + off);  off += (size_t)N_NODES * KK * 2;       // 10.5 MB
    ushort_t* buf = (ushort_t*)(w + off);  off += (size_t)NE * KK * 2;            // 78.6 MB
    ushort_t* Zb  = (ushort_t*)(w + off);  off += (size_t)N_ESLOT * 384 * 2;      // 25.2 MB
    int* cnt  = (int*)(w + off);  off += (size_t)(NKEY + 1) * 4 + 252; off &= ~(size_t)255;
    int* rank = (int*)(w + off);  off += (size_t)NE * 4;
    int* eidx = (int*)(w + off);  off += (size_t)NE * 4;

    const ushort_t* W1pack = pack;
    const ushort_t* W2pack = pack + (size_t)1536 * 8;
    const ushort_t* HWT    = pack + (size_t)(1536 + 3072) * 8;
    const ushort_t* GT     = pack + (size_t)(1536 + 3072 + 4096) * 8;

    hipMemsetAsync(cnt, 0, (size_t)(NKEY + 1) * 4, stream);

    prep_kernel<<<85, 256, 0, stream>>>(
        w_n_W1, w_same_W1, w_anti_W1, w_n_W2, w_same_W2, w_anti_W2,
        h_W, g_n_W, g_same_W, g_anti_W,
        w_n_b1, w_same_b1, w_anti_b1, w_n_b2, w_same_b2, w_anti_b2,
        (ushort_t*)pack, b1cat, b2cat);

    hx_nuc_b<<<1024, 256, 0, stream>>>(nuc, hxb);
    hx_elec_mfma<<<N_ESLOT / 64, 256, 0, stream>>>(elec, HWT, h_b, hxb);

    hist_kernel<<<NE / 256, 256, 0, stream>>>(receivers, e_type, cnt, rank);
    scan_kernel<<<1, 1024, 0, stream>>>(cnt);
    scatter_kernel<<<NE / 256, 256, 0, stream>>>(receivers, e_type, cnt, rank, eidx);

    edge_stage1<<<1200, 256, 0, stream>>>(dist, e_type, (const uint4*)W1pack, b1cat, buf);
    edge_stage2<<<1200, 256, 0, stream>>>(e_type, senders, (const uint4*)W2pack, b2cat, hxb, buf);

    zgather_kernel<<<2048, 256, 0, stream>>>(cnt, eidx, buf, Zb);

    gout_mfma<<<N_ESLOT / 64, 256, 0, stream>>>(Zb, elec, GT,
        g_n_b, g_same_b, g_anti_b, out);
}

// Round 4
// 352.925 us; speedup vs baseline: 2.5792x; 1.2233x over previous
//
#include <hip/hip_runtime.h>
#include <hip/hip_bf16.h>
#include <math.h>

#define NB      2048
#define N_NUC   4
#define N_ELEC  16
#define N_PART  20
#define N_NODES (NB * N_PART)     // 40960
#define NE      307200
#define DD      64
#define KK      128
#define EMB     256
#define N_ESLOT (NB * N_ELEC)     // 32768
#define NKEY    (N_ESLOT * 3)     // 98304
#define TRS     76                // LDS transpose row stride (ushorts)

typedef __attribute__((ext_vector_type(8))) short bf16x8;
typedef __attribute__((ext_vector_type(4))) float f32x4;
typedef unsigned short ushort_t;

__device__ __forceinline__ float ssp_f(float x) {
    float sp = fmaxf(x, 0.0f) + log1pf(expf(-fabsf(x)));
    return sp - 0.6931471805599453f;
}
__device__ __forceinline__ unsigned short f2b(float f) {
    union { float f; unsigned int u; } v; v.f = f;
    unsigned int r = (v.u + 0x7fffu + ((v.u >> 16) & 1u)) >> 16;
    return (unsigned short)r;
}
__device__ __forceinline__ float b2f(unsigned short u) {
    union { unsigned int u; float f; } v; v.u = ((unsigned int)u) << 16;
    return v.f;
}

// ================= prep: pack weights into MFMA-fragment layout (bf16) =================
// chunk c holds 16B = 8 bf16: elem j = W[k][n], k = ks*32+(lane>>4)*8+j, n = nt*16+(lane&15).
__global__ __launch_bounds__(256) void prep_kernel(
    const float* __restrict__ w_n_W1, const float* __restrict__ w_same_W1, const float* __restrict__ w_anti_W1,
    const float* __restrict__ w_n_W2, const float* __restrict__ w_same_W2, const float* __restrict__ w_anti_W2,
    const float* __restrict__ h_W,
    const float* __restrict__ g_n_W, const float* __restrict__ g_same_W, const float* __restrict__ g_anti_W,
    const float* __restrict__ w_n_b1, const float* __restrict__ w_same_b1, const float* __restrict__ w_anti_b1,
    const float* __restrict__ w_n_b2, const float* __restrict__ w_same_b2, const float* __restrict__ w_anti_b2,
    ushort_t* __restrict__ pack, float* __restrict__ b1cat, float* __restrict__ b2cat)
{
    int c = blockIdx.x * 256 + threadIdx.x;
    if (c < 1536) {                       // W1pack: nt 0..11 (n=192), ks 0..1
        int lane = c & 63, ks = (c >> 6) & 1, nt = c >> 7;
        ushort_t* dst = pack + (size_t)c * 8;
#pragma unroll
        for (int j = 0; j < 8; ++j) {
            int k = ks * 32 + ((lane >> 4) << 3) + j;
            int n = nt * 16 + (lane & 15);
            float v = (n < 64) ? w_n_W1[k * 64 + n]
                   : (n < 128) ? w_same_W1[k * 64 + n - 64]
                               : w_anti_W1[k * 64 + n - 128];
            dst[j] = f2b(v);
        }
    } else if (c < 1536 + 3072) {         // W2pack: nt 0..23 (n=384), ks 0..1
        int c2 = c - 1536;
        int lane = c2 & 63, ks = (c2 >> 6) & 1, nt = c2 >> 7;
        ushort_t* dst = pack + (size_t)c * 8;
#pragma unroll
        for (int j = 0; j < 8; ++j) {
            int k = ks * 32 + ((lane >> 4) << 3) + j;
            int n = nt * 16 + (lane & 15);
            float v = (n < 128) ? w_n_W2[k * KK + n]
                   : (n < 256) ? w_same_W2[k * KK + n - 128]
                               : w_anti_W2[k * KK + n - 256];
            dst[j] = f2b(v);
        }
    } else if (c < 1536 + 3072 + 4096) {  // HWT: nt 0..7 (n=128), ks 0..7
        int c3 = c - (1536 + 3072);
        int lane = c3 & 63, ks = (c3 >> 6) & 7, nt = c3 >> 9;
        ushort_t* dst = pack + (size_t)c * 8;
#pragma unroll
        for (int j = 0; j < 8; ++j) {
            int k = ks * 32 + ((lane >> 4) << 3) + j;
            int n = nt * 16 + (lane & 15);
            dst[j] = f2b(h_W[k * KK + n]);
        }
    } else if (c < 20992) {               // GT: nt 0..15 (n=256), ks 0..11 (k=384)
        int c4 = c - (1536 + 3072 + 4096);
        int lane = c4 & 63, ks = (c4 >> 6) % 12, nt = c4 / 768;
        ushort_t* dst = pack + (size_t)c * 8;
#pragma unroll
        for (int j = 0; j < 8; ++j) {
            int k = ks * 32 + ((lane >> 4) << 3) + j;
            int n = nt * 16 + (lane & 15);
            float v = (k < 128) ? g_n_W[k * EMB + n]
                   : (k < 256) ? g_same_W[(k - 128) * EMB + n]
                               : g_anti_W[(k - 256) * EMB + n];
            dst[j] = f2b(v);
        }
    } else if (c < 20992 + 192) {
        int i = c - 20992;
        b1cat[i] = (i < 64) ? w_n_b1[i] : (i < 128) ? w_same_b1[i - 64] : w_anti_b1[i - 128];
    } else if (c < 20992 + 192 + 384) {
        int i = c - 20992 - 192;
        b2cat[i] = (i < 128) ? w_n_b2[i] : (i < 256) ? w_same_b2[i - 128] : w_anti_b2[i - 256];
    }
}

// ================= hx build (PERMUTED inner layout: pos(c) = (c&15)*8 + (c>>4)) =================
__global__ __launch_bounds__(256) void hx_nuc_perm(
    const float* __restrict__ nuc, ushort_t* __restrict__ hxb)
{
    int t = blockIdx.x * 256 + threadIdx.x;   // 0..131071
    int nn = t >> 4;                           // nuc row 0..8191
    int l  = t & 15;
    int node = (nn >> 2) * N_PART + (nn & 3);
    const float* src = nuc + (size_t)nn * KK;
    bf16x8 o;
#pragma unroll
    for (int j = 0; j < 8; ++j) o[j] = (short)f2b(src[l + 16 * j]);
    *(bf16x8*)(hxb + (size_t)node * KK + l * 8) = o;
}

__global__ __launch_bounds__(256) void hx_elec_mfma(
    const float* __restrict__ elec, const ushort_t* __restrict__ HWT,
    const float* __restrict__ h_b, ushort_t* __restrict__ hxb)
{
    int tid = threadIdx.x;
    int lane = tid & 63;
    int l15 = lane & 15, l4 = lane >> 4;
    int row0 = blockIdx.x * 64 + (tid >> 6) * 16;

    bf16x8 a[8];
    const float* ep = elec + (size_t)(row0 + l15) * EMB + l4 * 8;
#pragma unroll
    for (int ks = 0; ks < 8; ++ks) {
        float4 v0 = *(const float4*)(ep + ks * 32);
        float4 v1 = *(const float4*)(ep + ks * 32 + 4);
        bf16x8 av;
        av[0] = (short)f2b(v0.x); av[1] = (short)f2b(v0.y);
        av[2] = (short)f2b(v0.z); av[3] = (short)f2b(v0.w);
        av[4] = (short)f2b(v1.x); av[5] = (short)f2b(v1.y);
        av[6] = (short)f2b(v1.z); av[7] = (short)f2b(v1.w);
        a[ks] = av;
    }

    f32x4 acc[8];
#pragma unroll
    for (int nt = 0; nt < 8; ++nt) acc[nt] = (f32x4)(0.0f);
#pragma unroll
    for (int nt = 0; nt < 8; ++nt) {
#pragma unroll
        for (int ks = 0; ks < 8; ++ks) {
            bf16x8 b = *(const bf16x8*)(HWT + ((size_t)(nt * 8 + ks) * 64 + lane) * 8);
            acc[nt] = __builtin_amdgcn_mfma_f32_16x16x32_bf16(a[ks], b, acc[nt], 0, 0, 0);
        }
    }
#pragma unroll
    for (int nt = 0; nt < 8; ++nt) {
        int n = nt * 16 + l15;
        float hb = h_b[n];
#pragma unroll
        for (int r = 0; r < 4; ++r) {
            int erow = row0 + l4 * 4 + r;
            int node = (erow >> 4) * N_PART + N_NUC + (erow & 15);
            hxb[(size_t)node * KK + l15 * 8 + nt] = f2b(acc[nt][r] + hb);   // permuted
        }
    }
}

// ================= sort by (type, slot), segments padded to x16 =================
__global__ __launch_bounds__(256) void hist_kernel(
    const int* __restrict__ receivers, const int* __restrict__ e_type,
    int* __restrict__ cnt, int* __restrict__ rank)
{
    int e = blockIdx.x * 256 + threadIdx.x;
    if (e >= NE) return;
    int r = receivers[e];
    int bb = r / N_PART;
    int p = r - bb * N_PART;
    if (p >= N_NUC) {
        int et = e_type[e];
        int t = (et == 1) ? 0 : ((et == 3) ? 1 : 2);
        int key = t * N_ESLOT + (bb * N_ELEC + p - N_NUC);
        rank[e] = atomicAdd(&cnt[key], 1);
    } else {
        rank[e] = -1;
    }
}

__global__ __launch_bounds__(1024) void scan_pad_kernel(int* __restrict__ cnt, int* __restrict__ seg)
{
    __shared__ int part[1024];
    __shared__ int shS1, shC2, shTot;
    int t = threadIdx.x;
    int base = t * (NKEY / 1024);   // 96 each
    int s = 0;
    for (int i = 0; i < NKEY / 1024; ++i) s += cnt[base + i];
    part[t] = s;
    __syncthreads();
    for (int off = 1; off < 1024; off <<= 1) {
        int add = (t >= off) ? part[t - off] : 0;
        __syncthreads();
        part[t] += add;
        __syncthreads();
    }
    int run = part[t] - s;          // exclusive prefix
    for (int i = 0; i < NKEY / 1024; ++i) {
        int idx = base + i;
        int c = cnt[idx];
        if (idx == N_ESLOT)     shS1 = run;
        if (idx == 2 * N_ESLOT) shC2 = run;
        cnt[idx] = run;
        run += c;
    }
    if (t == 1023) shTot = run;
    __syncthreads();
    int S1 = shS1, C2 = shC2, tot = shTot;
    int pad1 = (16 - (S1 & 15)) & 15;
    int pad2 = (16 - ((C2 + pad1) & 15)) & 15;
    for (int i = 0; i < NKEY / 1024; ++i) {
        int idx = base + i;
        int add = (idx >= 2 * N_ESLOT) ? (pad1 + pad2) : ((idx >= N_ESLOT) ? pad1 : 0);
        if (add) cnt[idx] += add;
    }
    if (t == 0) {
        seg[0] = 0;
        seg[1] = S1 + pad1;
        seg[2] = C2 + pad1 + pad2;
        seg[3] = tot + pad1 + pad2;
        cnt[NKEY] = tot + pad1 + pad2;
    }
}

__global__ __launch_bounds__(256) void scatter_kernel(
    const int* __restrict__ receivers, const int* __restrict__ e_type,
    const int* __restrict__ cnt, const int* __restrict__ rank, int* __restrict__ eidx)
{
    int e = blockIdx.x * 256 + threadIdx.x;
    if (e >= NE) return;
    int rk = rank[e];
    if (rk < 0) return;
    int r = receivers[e];
    int bb = r / N_PART;
    int p = r - bb * N_PART;
    int et = e_type[e];
    int t = (et == 1) ? 0 : ((et == 3) ? 1 : 2);
    int key = t * N_ESLOT + (bb * N_ELEC + p - N_NUC);
    eidx[cnt[key] + rk] = e;
}

// ================= fused edge kernel: weh rows in sorted order =================
// wave per 16-edge tile (type-uniform thanks to padding). B-frags read from global pack (L1/L2).
__global__ __launch_bounds__(256) void edge_fused(
    const float* __restrict__ dist, const int* __restrict__ senders,
    const int* __restrict__ eidx, const int* __restrict__ seg,
    const bf16x8* __restrict__ W1p, const float* __restrict__ b1cat,
    const bf16x8* __restrict__ W2p, const float* __restrict__ b2cat,
    const ushort_t* __restrict__ hxb, ushort_t* __restrict__ buf)
{
    __shared__ ushort_t tr[4][16 * TRS];
    int tid = threadIdx.x;
    int wave = tid >> 6, lane = tid & 63;
    int l15 = lane & 15, l4 = lane >> 4;
    int tile = blockIdx.x * 4 + wave;
    int total = seg[3];
    if (tile * 16 >= total) return;
    int t = (tile * 16 >= seg[1]) + (tile * 16 >= seg[2]);

    int e = eidx[tile * 16 + l15];
    int valid = (e >= 0) ? 1 : 0;
    int ec = valid ? e : 0;
    int snd = senders[ec];

    // A-frags from dist (gathered row, 64B/lane)
    bf16x8 a0, a1;
    {
        const float* dp = dist + (size_t)ec * DD + l4 * 8;
        float4 v0 = *(const float4*)(dp);
        float4 v1 = *(const float4*)(dp + 4);
        float4 v2 = *(const float4*)(dp + 32);
        float4 v3 = *(const float4*)(dp + 36);
        a0[0] = (short)f2b(v0.x); a0[1] = (short)f2b(v0.y);
        a0[2] = (short)f2b(v0.z); a0[3] = (short)f2b(v0.w);
        a0[4] = (short)f2b(v1.x); a0[5] = (short)f2b(v1.y);
        a0[6] = (short)f2b(v1.z); a0[7] = (short)f2b(v1.w);
        a1[0] = (short)f2b(v2.x); a1[1] = (short)f2b(v2.y);
        a1[2] = (short)f2b(v2.z); a1[3] = (short)f2b(v2.w);
        a1[4] = (short)f2b(v3.x); a1[5] = (short)f2b(v3.y);
        a1[6] = (short)f2b(v3.z); a1[7] = (short)f2b(v3.w);
    }

    // h1 = ssp(dist @ W1[t] + b1[t])  (8 MFMA)
    f32x4 ah[4];
#pragma unroll
    for (int q = 0; q < 4; ++q) ah[q] = (f32x4)(0.0f);
    const bf16x8* W1b = W1p + (size_t)(t * 4) * 2 * 64;
#pragma unroll
    for (int q = 0; q < 4; ++q) {
        bf16x8 b0 = W1b[(q * 2 + 0) * 64 + lane];
        bf16x8 b1v = W1b[(q * 2 + 1) * 64 + lane];
        ah[q] = __builtin_amdgcn_mfma_f32_16x16x32_bf16(a0, b0, ah[q], 0, 0, 0);
        ah[q] = __builtin_amdgcn_mfma_f32_16x16x32_bf16(a1, b1v, ah[q], 0, 0, 0);
    }

    // bias + ssp + per-wave LDS transpose (C-frag -> A-frag)
    ushort_t* trw = tr[wave];
#pragma unroll
    for (int q = 0; q < 4; ++q) {
        float bv = b1cat[t * 64 + q * 16 + l15];
#pragma unroll
        for (int r = 0; r < 4; ++r) {
            trw[(l4 * 4 + r) * TRS + q * 16 + l15] = f2b(ssp_f(ah[q][r] + bv));
        }
    }
    bf16x8 a2_0 = *(const bf16x8*)&trw[l15 * TRS + l4 * 8];
    bf16x8 a2_1 = *(const bf16x8*)&trw[l15 * TRS + 32 + l4 * 8];

    // weh = h1 @ W2[t] + b2[t]  (16 MFMA)
    f32x4 aw[8];
#pragma unroll
    for (int n = 0; n < 8; ++n) aw[n] = (f32x4)(0.0f);
    const bf16x8* W2b = W2p + (size_t)(t * 8) * 2 * 64;
#pragma unroll
    for (int n = 0; n < 8; ++n) {
        bf16x8 b0 = W2b[(n * 2 + 0) * 64 + lane];
        bf16x8 b1v = W2b[(n * 2 + 1) * 64 + lane];
        aw[n] = __builtin_amdgcn_mfma_f32_16x16x32_bf16(a2_0, b0, aw[n], 0, 0, 0);
        aw[n] = __builtin_amdgcn_mfma_f32_16x16x32_bf16(a2_1, b1v, aw[n], 0, 0, 0);
    }
    float bw[8];
#pragma unroll
    for (int n = 0; n < 8; ++n) bw[n] = b2cat[t * KK + n * 16 + l15];

    // epilogue: * hx[sender] (permuted b128 gather), store permuted b128 (zeros for pads)
#pragma unroll
    for (int r = 0; r < 4; ++r) {
        int m = l4 * 4 + r;
        int sdr = __shfl(snd, m);
        int vr  = __shfl(valid, m);
        bf16x8 hv = *(const bf16x8*)(hxb + (size_t)sdr * KK + l15 * 8);
        bf16x8 o;
#pragma unroll
        for (int n = 0; n < 8; ++n) {
            float w = aw[n][r] + bw[n];
            float val = vr ? w * b2f((unsigned short)hv[n]) : 0.0f;
            o[n] = (short)f2b(val);
        }
        *(bf16x8*)(buf + (size_t)(tile * 16 + m) * KK + l15 * 8) = o;
    }
}

// ================= zgather: contiguous bucket ranges, un-permute on write =================
__global__ __launch_bounds__(256) void zgather2(
    const int* __restrict__ cnt, const ushort_t* __restrict__ buf, ushort_t* __restrict__ Zb)
{
    int tid = threadIdx.x;
    int lane = tid & 63;
    int wid = blockIdx.x * 4 + (tid >> 6);
    int nw = gridDim.x * 4;

    int p0 = 2 * lane, p1 = 2 * lane + 1;
    int c0 = (p0 >> 3) + (p0 & 7) * 16;
    int c1 = (p1 >> 3) + (p1 & 7) * 16;

    for (int slot = wid; slot < N_ESLOT; slot += nw) {
#pragma unroll 3
        for (int t = 0; t < 3; ++t) {
            int lo = cnt[t * N_ESLOT + slot];
            int hi = cnt[t * N_ESLOT + slot + 1];
            float acc0 = 0.0f, acc1 = 0.0f;
            for (int i = lo; i < hi; ++i) {
                unsigned int v = *(const unsigned int*)(buf + (size_t)i * KK + 2 * lane);
                acc0 += b2f((unsigned short)(v & 0xffff));
                acc1 += b2f((unsigned short)(v >> 16));
            }
            Zb[(size_t)slot * 384 + t * KK + c0] = f2b(acc0);
            Zb[(size_t)slot * 384 + t * KK + c1] = f2b(acc1);
        }
    }
}

// ================= gout: out = elec + Zb @ GT + gb (MFMA) =================
__global__ __launch_bounds__(256) void gout_mfma(
    const ushort_t* __restrict__ Zb, const float* __restrict__ elec,
    const ushort_t* __restrict__ GT,
    const float* __restrict__ g_n_b, const float* __restrict__ g_same_b, const float* __restrict__ g_anti_b,
    float* __restrict__ out)
{
    int tid = threadIdx.x;
    int lane = tid & 63;
    int l15 = lane & 15, l4 = lane >> 4;
    int row0 = blockIdx.x * 64 + (tid >> 6) * 16;

    bf16x8 a[12];
    const ushort_t* zp = Zb + (size_t)(row0 + l15) * 384 + l4 * 8;
#pragma unroll
    for (int ks = 0; ks < 12; ++ks)
        a[ks] = *(const bf16x8*)(zp + ks * 32);

    f32x4 acc[16];
#pragma unroll
    for (int nt = 0; nt < 16; ++nt) acc[nt] = (f32x4)(0.0f);
#pragma unroll
    for (int nt = 0; nt < 16; ++nt) {
#pragma unroll
        for (int ks = 0; ks < 12; ++ks) {
            bf16x8 b = *(const bf16x8*)(GT + ((size_t)(nt * 12 + ks) * 64 + lane) * 8);
            acc[nt] = __builtin_amdgcn_mfma_f32_16x16x32_bf16(a[ks], b, acc[nt], 0, 0, 0);
        }
    }

#pragma unroll
    for (int nt = 0; nt < 16; ++nt) {
        int n = nt * 16 + l15;
        float gb = g_n_b[n] + g_same_b[n] + g_anti_b[n];
#pragma unroll
        for (int r = 0; r < 4; ++r) {
            size_t row = row0 + l4 * 4 + r;
            out[row * EMB + n] = elec[row * EMB + n] + acc[nt][r] + gb;
        }
    }
}

extern "C" void kernel_launch(void* const* d_in, const int* in_sizes, int n_in,
                              void* d_out, int out_size, void* d_ws, size_t ws_size,
                              hipStream_t stream) {
    const float* nuc       = (const float*)d_in[0];
    const float* elec      = (const float*)d_in[1];
    const float* dist      = (const float*)d_in[2];
    const int*   e_type    = (const int*)d_in[3];
    const int*   senders   = (const int*)d_in[4];
    const int*   receivers = (const int*)d_in[5];
    const float* w_same_W1 = (const float*)d_in[6];
    const float* w_same_b1 = (const float*)d_in[7];
    const float* w_same_W2 = (const float*)d_in[8];
    const float* w_same_b2 = (const float*)d_in[9];
    const float* w_anti_W1 = (const float*)d_in[10];
    const float* w_anti_b1 = (const float*)d_in[11];
    const float* w_anti_W2 = (const float*)d_in[12];
    const float* w_anti_b2 = (const float*)d_in[13];
    const float* w_n_W1    = (const float*)d_in[14];
    const float* w_n_b1    = (const float*)d_in[15];
    const float* w_n_W2    = (const float*)d_in[16];
    const float* w_n_b2    = (const float*)d_in[17];
    const float* h_W       = (const float*)d_in[18];
    const float* h_b       = (const float*)d_in[19];
    const float* g_same_W  = (const float*)d_in[20];
    const float* g_same_b  = (const float*)d_in[21];
    const float* g_anti_W  = (const float*)d_in[22];
    const float* g_anti_b  = (const float*)d_in[23];
    const float* g_n_W     = (const float*)d_in[24];
    const float* g_n_b     = (const float*)d_in[25];

    float* out = (float*)d_out;

    // ---- workspace layout ----
    char* w = (char*)d_ws;
    ushort_t* pack = (ushort_t*)w;                         // 20992*16 = 335,872 B
    size_t off = 20992 * 16;
    float* b1cat = (float*)(w + off);  off += 192 * 4;
    float* b2cat = (float*)(w + off);  off += 384 * 4;
    int*   seg   = (int*)(w + off);    off += 4 * 4;
    off = (off + 255) & ~(size_t)255;
    ushort_t* hxb = (ushort_t*)(w + off);  off += (size_t)N_NODES * KK * 2;        // 10.5 MB
    ushort_t* buf = (ushort_t*)(w + off);  off += (size_t)(NE + 64) * KK * 2;      // 78.7 MB
    ushort_t* Zb  = (ushort_t*)(w + off);  off += (size_t)N_ESLOT * 384 * 2;       // 25.2 MB
    int* cnt  = (int*)(w + off);  off += (size_t)(NKEY + 1) * 4 + 252; off &= ~(size_t)255;
    int* rank = (int*)(w + off);  off += (size_t)NE * 4;
    int* eidx = (int*)(w + off);  off += (size_t)(NE + 64) * 4;

    const ushort_t* W1pack = pack;
    const ushort_t* W2pack = pack + (size_t)1536 * 8;
    const ushort_t* HWT    = pack + (size_t)(1536 + 3072) * 8;
    const ushort_t* GT     = pack + (size_t)(1536 + 3072 + 4096) * 8;

    hipMemsetAsync(cnt, 0, (size_t)(NKEY + 1) * 4, stream);
    hipMemsetAsync(eidx, 0xFF, (size_t)(NE + 64) * 4, stream);   // -1 pads

    prep_kernel<<<85, 256, 0, stream>>>(
        w_n_W1, w_same_W1, w_anti_W1, w_n_W2, w_same_W2, w_anti_W2,
        h_W, g_n_W, g_same_W, g_anti_W,
        w_n_b1, w_same_b1, w_anti_b1, w_n_b2, w_same_b2, w_anti_b2,
        (ushort_t*)pack, b1cat, b2cat);

    hx_nuc_perm<<<512, 256, 0, stream>>>(nuc, hxb);
    hx_elec_mfma<<<N_ESLOT / 64, 256, 0, stream>>>(elec, HWT, h_b, hxb);

    hist_kernel<<<NE / 256, 256, 0, stream>>>(receivers, e_type, cnt, rank);
    scan_pad_kernel<<<1, 1024, 0, stream>>>(cnt, seg);
    scatter_kernel<<<NE / 256, 256, 0, stream>>>(receivers, e_type, cnt, rank, eidx);

    edge_fused<<<(NE / 16 + 3 + 3) / 4 + 1, 256, 0, stream>>>(dist, senders, eidx, seg,
        (const bf16x8*)W1pack, b1cat, (const bf16x8*)W2pack, b2cat, hxb, buf);

    zgather2<<<2048, 256, 0, stream>>>(cnt, buf, Zb);

    gout_mfma<<<N_ESLOT / 64, 256, 0, stream>>>(Zb, elec, GT,
        g_n_b, g_same_b, g_anti_b, out);
}

// Round 5
// 209.439 us; speedup vs baseline: 4.3462x; 1.6851x over previous
//
#include <hip/hip_runtime.h>
#include <hip/hip_bf16.h>
#include <math.h>

#define NB      2048
#define N_NUC   4
#define N_ELEC  16
#define N_PART  20
#define N_NODES (NB * N_PART)     // 40960
#define NE      307200
#define DD      64
#define KK      128
#define EMB     256
#define N_ESLOT (NB * N_ELEC)     // 32768
#define NKEY    (N_ESLOT * 3)     // 98304
#define NSB     96                // scan blocks (NKEY/1024)
#define TRS     76                // LDS transpose row stride (ushorts)

typedef __attribute__((ext_vector_type(8))) short bf16x8;
typedef __attribute__((ext_vector_type(4))) float f32x4;
typedef unsigned short ushort_t;

__device__ __forceinline__ float ssp_f(float x) {
    float sp = fmaxf(x, 0.0f) + log1pf(expf(-fabsf(x)));
    return sp - 0.6931471805599453f;
}
__device__ __forceinline__ unsigned short f2b(float f) {
    union { float f; unsigned int u; } v; v.f = f;
    unsigned int r = (v.u + 0x7fffu + ((v.u >> 16) & 1u)) >> 16;
    return (unsigned short)r;
}
__device__ __forceinline__ float b2f(unsigned short u) {
    union { unsigned int u; float f; } v; v.u = ((unsigned int)u) << 16;
    return v.f;
}

// ================= prep: pack weights into MFMA-fragment layout (bf16) =================
__global__ __launch_bounds__(256) void prep_kernel(
    const float* __restrict__ w_n_W1, const float* __restrict__ w_same_W1, const float* __restrict__ w_anti_W1,
    const float* __restrict__ w_n_W2, const float* __restrict__ w_same_W2, const float* __restrict__ w_anti_W2,
    const float* __restrict__ h_W,
    const float* __restrict__ g_n_W, const float* __restrict__ g_same_W, const float* __restrict__ g_anti_W,
    const float* __restrict__ w_n_b1, const float* __restrict__ w_same_b1, const float* __restrict__ w_anti_b1,
    const float* __restrict__ w_n_b2, const float* __restrict__ w_same_b2, const float* __restrict__ w_anti_b2,
    ushort_t* __restrict__ pack, float* __restrict__ b1cat, float* __restrict__ b2cat)
{
    int c = blockIdx.x * 256 + threadIdx.x;
    if (c < 1536) {                       // W1pack: nt 0..11 (n=192), ks 0..1
        int lane = c & 63, ks = (c >> 6) & 1, nt = c >> 7;
        ushort_t* dst = pack + (size_t)c * 8;
#pragma unroll
        for (int j = 0; j < 8; ++j) {
            int k = ks * 32 + ((lane >> 4) << 3) + j;
            int n = nt * 16 + (lane & 15);
            float v = (n < 64) ? w_n_W1[k * 64 + n]
                   : (n < 128) ? w_same_W1[k * 64 + n - 64]
                               : w_anti_W1[k * 64 + n - 128];
            dst[j] = f2b(v);
        }
    } else if (c < 1536 + 3072) {         // W2pack: nt 0..23 (n=384), ks 0..1
        int c2 = c - 1536;
        int lane = c2 & 63, ks = (c2 >> 6) & 1, nt = c2 >> 7;
        ushort_t* dst = pack + (size_t)c * 8;
#pragma unroll
        for (int j = 0; j < 8; ++j) {
            int k = ks * 32 + ((lane >> 4) << 3) + j;
            int n = nt * 16 + (lane & 15);
            float v = (n < 128) ? w_n_W2[k * KK + n]
                   : (n < 256) ? w_same_W2[k * KK + n - 128]
                               : w_anti_W2[k * KK + n - 256];
            dst[j] = f2b(v);
        }
    } else if (c < 1536 + 3072 + 4096) {  // HWT: nt 0..7 (n=128), ks 0..7
        int c3 = c - (1536 + 3072);
        int lane = c3 & 63, ks = (c3 >> 6) & 7, nt = c3 >> 9;
        ushort_t* dst = pack + (size_t)c * 8;
#pragma unroll
        for (int j = 0; j < 8; ++j) {
            int k = ks * 32 + ((lane >> 4) << 3) + j;
            int n = nt * 16 + (lane & 15);
            dst[j] = f2b(h_W[k * KK + n]);
        }
    } else if (c < 20992) {               // GT: nt 0..15 (n=256), ks 0..11 (k=384)
        int c4 = c - (1536 + 3072 + 4096);
        int lane = c4 & 63, ks = (c4 >> 6) % 12, nt = c4 / 768;
        ushort_t* dst = pack + (size_t)c * 8;
#pragma unroll
        for (int j = 0; j < 8; ++j) {
            int k = ks * 32 + ((lane >> 4) << 3) + j;
            int n = nt * 16 + (lane & 15);
            float v = (k < 128) ? g_n_W[k * EMB + n]
                   : (k < 256) ? g_same_W[(k - 128) * EMB + n]
                               : g_anti_W[(k - 256) * EMB + n];
            dst[j] = f2b(v);
        }
    } else if (c < 20992 + 192) {
        int i = c - 20992;
        b1cat[i] = (i < 64) ? w_n_b1[i] : (i < 128) ? w_same_b1[i - 64] : w_anti_b1[i - 128];
    } else if (c < 20992 + 192 + 384) {
        int i = c - 20992 - 192;
        b2cat[i] = (i < 128) ? w_n_b2[i] : (i < 256) ? w_same_b2[i - 128] : w_anti_b2[i - 256];
    }
}

// ================= hx build (PERMUTED inner layout: pos(c) = (c&15)*8 + (c>>4)) =================
__global__ __launch_bounds__(256) void hx_nuc_perm(
    const float* __restrict__ nuc, ushort_t* __restrict__ hxb)
{
    int t = blockIdx.x * 256 + threadIdx.x;   // 0..131071
    int nn = t >> 4;                           // nuc row 0..8191
    int l  = t & 15;
    int node = (nn >> 2) * N_PART + (nn & 3);
    const float* src = nuc + (size_t)nn * KK;
    bf16x8 o;
#pragma unroll
    for (int j = 0; j < 8; ++j) o[j] = (short)f2b(src[l + 16 * j]);
    *(bf16x8*)(hxb + (size_t)node * KK + l * 8) = o;
}

__global__ __launch_bounds__(256) void hx_elec_mfma(
    const float* __restrict__ elec, const ushort_t* __restrict__ HWT,
    const float* __restrict__ h_b, ushort_t* __restrict__ hxb)
{
    int tid = threadIdx.x;
    int lane = tid & 63;
    int l15 = lane & 15, l4 = lane >> 4;
    int row0 = blockIdx.x * 64 + (tid >> 6) * 16;

    bf16x8 a[8];
    const float* ep = elec + (size_t)(row0 + l15) * EMB + l4 * 8;
#pragma unroll
    for (int ks = 0; ks < 8; ++ks) {
        float4 v0 = *(const float4*)(ep + ks * 32);
        float4 v1 = *(const float4*)(ep + ks * 32 + 4);
        bf16x8 av;
        av[0] = (short)f2b(v0.x); av[1] = (short)f2b(v0.y);
        av[2] = (short)f2b(v0.z); av[3] = (short)f2b(v0.w);
        av[4] = (short)f2b(v1.x); av[5] = (short)f2b(v1.y);
        av[6] = (short)f2b(v1.z); av[7] = (short)f2b(v1.w);
        a[ks] = av;
    }

    f32x4 acc[8];
#pragma unroll
    for (int nt = 0; nt < 8; ++nt) acc[nt] = (f32x4)(0.0f);
#pragma unroll
    for (int nt = 0; nt < 8; ++nt) {
#pragma unroll
        for (int ks = 0; ks < 8; ++ks) {
            bf16x8 b = *(const bf16x8*)(HWT + ((size_t)(nt * 8 + ks) * 64 + lane) * 8);
            acc[nt] = __builtin_amdgcn_mfma_f32_16x16x32_bf16(a[ks], b, acc[nt], 0, 0, 0);
        }
    }
#pragma unroll
    for (int nt = 0; nt < 8; ++nt) {
        int n = nt * 16 + l15;
        float hb = h_b[n];
#pragma unroll
        for (int r = 0; r < 4; ++r) {
            int erow = row0 + l4 * 4 + r;
            int node = (erow >> 4) * N_PART + N_NUC + (erow & 15);
            hxb[(size_t)node * KK + l15 * 8 + nt] = f2b(acc[nt][r] + hb);   // permuted
        }
    }
}

// ================= sort by (type, slot), segments padded to x16 =================
__global__ __launch_bounds__(256) void hist_kernel(
    const int* __restrict__ receivers, const int* __restrict__ e_type,
    int* __restrict__ cnt, int* __restrict__ rank)
{
    int e = blockIdx.x * 256 + threadIdx.x;
    if (e >= NE) return;
    int r = receivers[e];
    int bb = r / N_PART;
    int p = r - bb * N_PART;
    if (p >= N_NUC) {
        int et = e_type[e];
        int t = (et == 1) ? 0 : ((et == 3) ? 1 : 2);
        int key = t * N_ESLOT + (bb * N_ELEC + p - N_NUC);
        rank[e] = atomicAdd(&cnt[key], 1);
    } else {
        rank[e] = -1;
    }
}

// ---- hierarchical scan: local (96 blocks x 1024 elems) -> bsum (1 tiny) -> add ----
__global__ __launch_bounds__(256) void scan_local(int* __restrict__ cnt, int* __restrict__ bsum)
{
    __shared__ int sh[256];
    int t = threadIdx.x, bid = blockIdx.x;
    int base = bid * 1024 + t * 4;
    int4 v = *(const int4*)&cnt[base];
    int s = v.x + v.y + v.z + v.w;
    sh[t] = s;
    __syncthreads();
    for (int off = 1; off < 256; off <<= 1) {
        int add = (t >= off) ? sh[t - off] : 0;
        __syncthreads();
        sh[t] += add;
        __syncthreads();
    }
    int pre = sh[t] - s;
    int4 o;
    o.x = pre; o.y = pre + v.x; o.z = o.y + v.y; o.w = o.z + v.z;
    *(int4*)&cnt[base] = o;
    if (t == 255) bsum[bid] = sh[255];
}

__global__ __launch_bounds__(128) void scan_bsum(int* __restrict__ bsum, int* __restrict__ seg, int* __restrict__ cnt)
{
    __shared__ int sh[128];
    __shared__ int S1s, C2s, tots;
    int t = threadIdx.x;
    int v = (t < NSB) ? bsum[t] : 0;
    sh[t] = v;
    __syncthreads();
    for (int off = 1; off < 128; off <<= 1) {
        int add = (t >= off) ? sh[t - off] : 0;
        __syncthreads();
        sh[t] += add;
        __syncthreads();
    }
    int pre = sh[t] - v;      // exclusive prefix over block sums
    if (t == 31) S1s = sh[31];    // total of type-0 segment (blocks 0..31)
    if (t == 63) C2s = sh[63];    // total through type-1 segment
    if (t == NSB - 1) tots = sh[NSB - 1];
    __syncthreads();
    int S1 = S1s, C2 = C2s, tot = tots;
    int pad1 = (16 - (S1 & 15)) & 15;
    int pad2 = (16 - ((C2 + pad1) & 15)) & 15;
    if (t < NSB) {
        int add = ((t >= 32) ? pad1 : 0) + ((t >= 64) ? pad2 : 0);
        bsum[t] = pre + add;
    }
    if (t == 0) {
        seg[0] = 0;
        seg[1] = S1 + pad1;
        seg[2] = C2 + pad1 + pad2;
        seg[3] = tot + pad1 + pad2;
        cnt[NKEY] = tot + pad1 + pad2;
    }
}

__global__ __launch_bounds__(256) void scan_add(int* __restrict__ cnt, const int* __restrict__ bsum)
{
    int bid = blockIdx.x;
    int off = bsum[bid];
    int base = bid * 1024 + threadIdx.x * 4;
    int4 v = *(const int4*)&cnt[base];
    v.x += off; v.y += off; v.z += off; v.w += off;
    *(int4*)&cnt[base] = v;
}

__global__ __launch_bounds__(256) void scatter_kernel(
    const int* __restrict__ receivers, const int* __restrict__ e_type,
    const int* __restrict__ cnt, const int* __restrict__ rank, int* __restrict__ eidx)
{
    int e = blockIdx.x * 256 + threadIdx.x;
    if (e >= NE) return;
    int rk = rank[e];
    if (rk < 0) return;
    int r = receivers[e];
    int bb = r / N_PART;
    int p = r - bb * N_PART;
    int et = e_type[e];
    int t = (et == 1) ? 0 : ((et == 3) ? 1 : 2);
    int key = t * N_ESLOT + (bb * N_ELEC + p - N_NUC);
    eidx[cnt[key] + rk] = e;
}

// ================= fused edge kernel: weh rows in sorted order =================
__global__ __launch_bounds__(256) void edge_fused(
    const float* __restrict__ dist, const int* __restrict__ senders,
    const int* __restrict__ eidx, const int* __restrict__ seg,
    const bf16x8* __restrict__ W1p, const float* __restrict__ b1cat,
    const bf16x8* __restrict__ W2p, const float* __restrict__ b2cat,
    const ushort_t* __restrict__ hxb, ushort_t* __restrict__ buf)
{
    __shared__ ushort_t tr[4][16 * TRS];
    int tid = threadIdx.x;
    int wave = tid >> 6, lane = tid & 63;
    int l15 = lane & 15, l4 = lane >> 4;
    int tile = blockIdx.x * 4 + wave;
    int total = seg[3];
    if (tile * 16 >= total) return;
    int t = (tile * 16 >= seg[1]) + (tile * 16 >= seg[2]);

    int e = eidx[tile * 16 + l15];
    int valid = (e >= 0) ? 1 : 0;
    int ec = valid ? e : 0;
    int snd = senders[ec];

    // A-frags from dist (gathered row, 64B/lane)
    bf16x8 a0, a1;
    {
        const float* dp = dist + (size_t)ec * DD + l4 * 8;
        float4 v0 = *(const float4*)(dp);
        float4 v1 = *(const float4*)(dp + 4);
        float4 v2 = *(const float4*)(dp + 32);
        float4 v3 = *(const float4*)(dp + 36);
        a0[0] = (short)f2b(v0.x); a0[1] = (short)f2b(v0.y);
        a0[2] = (short)f2b(v0.z); a0[3] = (short)f2b(v0.w);
        a0[4] = (short)f2b(v1.x); a0[5] = (short)f2b(v1.y);
        a0[6] = (short)f2b(v1.z); a0[7] = (short)f2b(v1.w);
        a1[0] = (short)f2b(v2.x); a1[1] = (short)f2b(v2.y);
        a1[2] = (short)f2b(v2.z); a1[3] = (short)f2b(v2.w);
        a1[4] = (short)f2b(v3.x); a1[5] = (short)f2b(v3.y);
        a1[6] = (short)f2b(v3.z); a1[7] = (short)f2b(v3.w);
    }

    // h1 = ssp(dist @ W1[t] + b1[t])  (8 MFMA)
    f32x4 ah[4];
#pragma unroll
    for (int q = 0; q < 4; ++q) ah[q] = (f32x4)(0.0f);
    const bf16x8* W1b = W1p + (size_t)(t * 4) * 2 * 64;
#pragma unroll
    for (int q = 0; q < 4; ++q) {
        bf16x8 b0 = W1b[(q * 2 + 0) * 64 + lane];
        bf16x8 b1v = W1b[(q * 2 + 1) * 64 + lane];
        ah[q] = __builtin_amdgcn_mfma_f32_16x16x32_bf16(a0, b0, ah[q], 0, 0, 0);
        ah[q] = __builtin_amdgcn_mfma_f32_16x16x32_bf16(a1, b1v, ah[q], 0, 0, 0);
    }

    // bias + ssp + per-wave LDS transpose (C-frag -> A-frag)
    ushort_t* trw = tr[wave];
#pragma unroll
    for (int q = 0; q < 4; ++q) {
        float bv = b1cat[t * 64 + q * 16 + l15];
#pragma unroll
        for (int r = 0; r < 4; ++r) {
            trw[(l4 * 4 + r) * TRS + q * 16 + l15] = f2b(ssp_f(ah[q][r] + bv));
        }
    }
    bf16x8 a2_0 = *(const bf16x8*)&trw[l15 * TRS + l4 * 8];
    bf16x8 a2_1 = *(const bf16x8*)&trw[l15 * TRS + 32 + l4 * 8];

    // weh = h1 @ W2[t] + b2[t]  (16 MFMA)
    f32x4 aw[8];
#pragma unroll
    for (int n = 0; n < 8; ++n) aw[n] = (f32x4)(0.0f);
    const bf16x8* W2b = W2p + (size_t)(t * 8) * 2 * 64;
#pragma unroll
    for (int n = 0; n < 8; ++n) {
        bf16x8 b0 = W2b[(n * 2 + 0) * 64 + lane];
        bf16x8 b1v = W2b[(n * 2 + 1) * 64 + lane];
        aw[n] = __builtin_amdgcn_mfma_f32_16x16x32_bf16(a2_0, b0, aw[n], 0, 0, 0);
        aw[n] = __builtin_amdgcn_mfma_f32_16x16x32_bf16(a2_1, b1v, aw[n], 0, 0, 0);
    }
    float bw[8];
#pragma unroll
    for (int n = 0; n < 8; ++n) bw[n] = b2cat[t * KK + n * 16 + l15];

    // epilogue: * hx[sender] (permuted b128 gather), store permuted b128 (zeros for pads)
#pragma unroll
    for (int r = 0; r < 4; ++r) {
        int m = l4 * 4 + r;
        int sdr = __shfl(snd, m);
        int vr  = __shfl(valid, m);
        bf16x8 hv = *(const bf16x8*)(hxb + (size_t)sdr * KK + l15 * 8);
        bf16x8 o;
#pragma unroll
        for (int n = 0; n < 8; ++n) {
            float w = aw[n][r] + bw[n];
            float val = vr ? w * b2f((unsigned short)hv[n]) : 0.0f;
            o[n] = (short)f2b(val);
        }
        *(bf16x8*)(buf + (size_t)(tile * 16 + m) * KK + l15 * 8) = o;
    }
}

// ================= zgather: contiguous bucket ranges, un-permute on write =================
__global__ __launch_bounds__(256) void zgather2(
    const int* __restrict__ cnt, const ushort_t* __restrict__ buf, ushort_t* __restrict__ Zb)
{
    int tid = threadIdx.x;
    int lane = tid & 63;
    int wid = blockIdx.x * 4 + (tid >> 6);
    int nw = gridDim.x * 4;

    int p0 = 2 * lane, p1 = 2 * lane + 1;
    int c0 = (p0 >> 3) + (p0 & 7) * 16;
    int c1 = (p1 >> 3) + (p1 & 7) * 16;

    for (int slot = wid; slot < N_ESLOT; slot += nw) {
#pragma unroll 3
        for (int t = 0; t < 3; ++t) {
            int lo = cnt[t * N_ESLOT + slot];
            int hi = cnt[t * N_ESLOT + slot + 1];
            float acc0 = 0.0f, acc1 = 0.0f;
            for (int i = lo; i < hi; ++i) {
                unsigned int v = *(const unsigned int*)(buf + (size_t)i * KK + 2 * lane);
                acc0 += b2f((unsigned short)(v & 0xffff));
                acc1 += b2f((unsigned short)(v >> 16));
            }
            Zb[(size_t)slot * 384 + t * KK + c0] = f2b(acc0);
            Zb[(size_t)slot * 384 + t * KK + c1] = f2b(acc1);
        }
    }
}

// ================= gout: out = elec + Zb @ GT + gb (MFMA) =================
__global__ __launch_bounds__(256) void gout_mfma(
    const ushort_t* __restrict__ Zb, const float* __restrict__ elec,
    const ushort_t* __restrict__ GT,
    const float* __restrict__ g_n_b, const float* __restrict__ g_same_b, const float* __restrict__ g_anti_b,
    float* __restrict__ out)
{
    int tid = threadIdx.x;
    int lane = tid & 63;
    int l15 = lane & 15, l4 = lane >> 4;
    int row0 = blockIdx.x * 64 + (tid >> 6) * 16;

    bf16x8 a[12];
    const ushort_t* zp = Zb + (size_t)(row0 + l15) * 384 + l4 * 8;
#pragma unroll
    for (int ks = 0; ks < 12; ++ks)
        a[ks] = *(const bf16x8*)(zp + ks * 32);

    f32x4 acc[16];
#pragma unroll
    for (int nt = 0; nt < 16; ++nt) acc[nt] = (f32x4)(0.0f);
#pragma unroll
    for (int nt = 0; nt < 16; ++nt) {
#pragma unroll
        for (int ks = 0; ks < 12; ++ks) {
            bf16x8 b = *(const bf16x8*)(GT + ((size_t)(nt * 12 + ks) * 64 + lane) * 8);
            acc[nt] = __builtin_amdgcn_mfma_f32_16x16x32_bf16(a[ks], b, acc[nt], 0, 0, 0);
        }
    }

#pragma unroll
    for (int nt = 0; nt < 16; ++nt) {
        int n = nt * 16 + l15;
        float gb = g_n_b[n] + g_same_b[n] + g_anti_b[n];
#pragma unroll
        for (int r = 0; r < 4; ++r) {
            size_t row = row0 + l4 * 4 + r;
            out[row * EMB + n] = elec[row * EMB + n] + acc[nt][r] + gb;
        }
    }
}

extern "C" void kernel_launch(void* const* d_in, const int* in_sizes, int n_in,
                              void* d_out, int out_size, void* d_ws, size_t ws_size,
                              hipStream_t stream) {
    const float* nuc       = (const float*)d_in[0];
    const float* elec      = (const float*)d_in[1];
    const float* dist      = (const float*)d_in[2];
    const int*   e_type    = (const int*)d_in[3];
    const int*   senders   = (const int*)d_in[4];
    const int*   receivers = (const int*)d_in[5];
    const float* w_same_W1 = (const float*)d_in[6];
    const float* w_same_b1 = (const float*)d_in[7];
    const float* w_same_W2 = (const float*)d_in[8];
    const float* w_same_b2 = (const float*)d_in[9];
    const float* w_anti_W1 = (const float*)d_in[10];
    const float* w_anti_b1 = (const float*)d_in[11];
    const float* w_anti_W2 = (const float*)d_in[12];
    const float* w_anti_b2 = (const float*)d_in[13];
    const float* w_n_W1    = (const float*)d_in[14];
    const float* w_n_b1    = (const float*)d_in[15];
    const float* w_n_W2    = (const float*)d_in[16];
    const float* w_n_b2    = (const float*)d_in[17];
    const float* h_W       = (const float*)d_in[18];
    const float* h_b       = (const float*)d_in[19];
    const float* g_same_W  = (const float*)d_in[20];
    const float* g_same_b  = (const float*)d_in[21];
    const float* g_anti_W  = (const float*)d_in[22];
    const float* g_anti_b  = (const float*)d_in[23];
    const float* g_n_W     = (const float*)d_in[24];
    const float* g_n_b     = (const float*)d_in[25];

    float* out = (float*)d_out;

    // ---- workspace layout ----
    char* w = (char*)d_ws;
    ushort_t* pack = (ushort_t*)w;                         // 20992*16 = 335,872 B
    size_t off = 20992 * 16;
    float* b1cat = (float*)(w + off);  off += 192 * 4;
    float* b2cat = (float*)(w + off);  off += 384 * 4;
    int*   seg   = (int*)(w + off);    off += 4 * 4;
    int*   bsum  = (int*)(w + off);    off += 128 * 4;
    off = (off + 255) & ~(size_t)255;
    ushort_t* hxb = (ushort_t*)(w + off);  off += (size_t)N_NODES * KK * 2;        // 10.5 MB
    ushort_t* buf = (ushort_t*)(w + off);  off += (size_t)(NE + 64) * KK * 2;      // 78.7 MB
    ushort_t* Zb  = (ushort_t*)(w + off);  off += (size_t)N_ESLOT * 384 * 2;       // 25.2 MB
    int* cnt  = (int*)(w + off);  off += (size_t)(NKEY + 1) * 4 + 252; off &= ~(size_t)255;
    int* rank = (int*)(w + off);  off += (size_t)NE * 4;
    int* eidx = (int*)(w + off);  off += (size_t)(NE + 64) * 4;

    const ushort_t* W1pack = pack;
    const ushort_t* W2pack = pack + (size_t)1536 * 8;
    const ushort_t* HWT    = pack + (size_t)(1536 + 3072) * 8;
    const ushort_t* GT     = pack + (size_t)(1536 + 3072 + 4096) * 8;

    hipMemsetAsync(cnt, 0, (size_t)(NKEY + 1) * 4, stream);
    hipMemsetAsync(eidx, 0xFF, (size_t)(NE + 64) * 4, stream);   // -1 pads

    prep_kernel<<<85, 256, 0, stream>>>(
        w_n_W1, w_same_W1, w_anti_W1, w_n_W2, w_same_W2, w_anti_W2,
        h_W, g_n_W, g_same_W, g_anti_W,
        w_n_b1, w_same_b1, w_anti_b1, w_n_b2, w_same_b2, w_anti_b2,
        (ushort_t*)pack, b1cat, b2cat);

    hx_nuc_perm<<<512, 256, 0, stream>>>(nuc, hxb);
    hx_elec_mfma<<<N_ESLOT / 64, 256, 0, stream>>>(elec, HWT, h_b, hxb);

    hist_kernel<<<NE / 256, 256, 0, stream>>>(receivers, e_type, cnt, rank);
    scan_local<<<NSB, 256, 0, stream>>>(cnt, bsum);
    scan_bsum<<<1, 128, 0, stream>>>(bsum, seg, cnt);
    scan_add<<<NSB, 256, 0, stream>>>(cnt, bsum);
    scatter_kernel<<<NE / 256, 256, 0, stream>>>(receivers, e_type, cnt, rank, eidx);

    edge_fused<<<(NE / 16 + 3 + 3) / 4 + 1, 256, 0, stream>>>(dist, senders, eidx, seg,
        (const bf16x8*)W1pack, b1cat, (const bf16x8*)W2pack, b2cat, hxb, buf);

    zgather2<<<2048, 256, 0, stream>>>(cnt, buf, Zb);

    gout_mfma<<<N_ESLOT / 64, 256, 0, stream>>>(Zb, elec, GT,
        g_n_b, g_same_b, g_anti_b, out);
}

// Round 6
// 165.396 us; speedup vs baseline: 5.5036x; 1.2663x over previous
//
#include <hip/hip_runtime.h>
#include <hip/hip_bf16.h>
#include <math.h>

#define NB      2048
#define N_NUC   4
#define N_ELEC  16
#define N_PART  20
#define N_NODES (NB * N_PART)     // 40960
#define NE      307200
#define DD      64
#define KK      128
#define EMB     256
#define N_ESLOT (NB * N_ELEC)     // 32768
#define NKEY    (N_ESLOT * 3)     // 98304
#define NSB     96                // scan blocks (NKEY/1024)
#define TRS     76                // LDS transpose row stride (ushorts)

typedef __attribute__((ext_vector_type(8))) short bf16x8;
typedef __attribute__((ext_vector_type(4))) float f32x4;
typedef unsigned short ushort_t;

__device__ __forceinline__ float ssp_f(float x) {
    float sp = fmaxf(x, 0.0f) + log1pf(expf(-fabsf(x)));
    return sp - 0.6931471805599453f;
}
__device__ __forceinline__ unsigned short f2b(float f) {
    union { float f; unsigned int u; } v; v.f = f;
    unsigned int r = (v.u + 0x7fffu + ((v.u >> 16) & 1u)) >> 16;
    return (unsigned short)r;
}
__device__ __forceinline__ float b2f(unsigned short u) {
    union { unsigned int u; float f; } v; v.u = ((unsigned int)u) << 16;
    return v.f;
}

// ================= prep: pack weights into MFMA-fragment layout (bf16) =================
__global__ __launch_bounds__(256) void prep_kernel(
    const float* __restrict__ w_n_W1, const float* __restrict__ w_same_W1, const float* __restrict__ w_anti_W1,
    const float* __restrict__ w_n_W2, const float* __restrict__ w_same_W2, const float* __restrict__ w_anti_W2,
    const float* __restrict__ h_W,
    const float* __restrict__ g_n_W, const float* __restrict__ g_same_W, const float* __restrict__ g_anti_W,
    const float* __restrict__ w_n_b1, const float* __restrict__ w_same_b1, const float* __restrict__ w_anti_b1,
    const float* __restrict__ w_n_b2, const float* __restrict__ w_same_b2, const float* __restrict__ w_anti_b2,
    const float* __restrict__ g_n_b, const float* __restrict__ g_same_b, const float* __restrict__ g_anti_b,
    ushort_t* __restrict__ pack, float* __restrict__ b1cat, float* __restrict__ b2cat,
    float* __restrict__ gbsum)
{
    int c = blockIdx.x * 256 + threadIdx.x;
    if (c < 1536) {                       // W1pack: nt 0..11 (n=192), ks 0..1
        int lane = c & 63, ks = (c >> 6) & 1, nt = c >> 7;
        ushort_t* dst = pack + (size_t)c * 8;
#pragma unroll
        for (int j = 0; j < 8; ++j) {
            int k = ks * 32 + ((lane >> 4) << 3) + j;
            int n = nt * 16 + (lane & 15);
            float v = (n < 64) ? w_n_W1[k * 64 + n]
                   : (n < 128) ? w_same_W1[k * 64 + n - 64]
                               : w_anti_W1[k * 64 + n - 128];
            dst[j] = f2b(v);
        }
    } else if (c < 1536 + 3072) {         // W2pack: nt 0..23 (n=384), ks 0..1
        int c2 = c - 1536;
        int lane = c2 & 63, ks = (c2 >> 6) & 1, nt = c2 >> 7;
        ushort_t* dst = pack + (size_t)c * 8;
#pragma unroll
        for (int j = 0; j < 8; ++j) {
            int k = ks * 32 + ((lane >> 4) << 3) + j;
            int n = nt * 16 + (lane & 15);
            float v = (n < 128) ? w_n_W2[k * KK + n]
                   : (n < 256) ? w_same_W2[k * KK + n - 128]
                               : w_anti_W2[k * KK + n - 256];
            dst[j] = f2b(v);
        }
    } else if (c < 1536 + 3072 + 4096) {  // HWT: nt 0..7 (n=128), ks 0..7
        int c3 = c - (1536 + 3072);
        int lane = c3 & 63, ks = (c3 >> 6) & 7, nt = c3 >> 9;
        ushort_t* dst = pack + (size_t)c * 8;
#pragma unroll
        for (int j = 0; j < 8; ++j) {
            int k = ks * 32 + ((lane >> 4) << 3) + j;
            int n = nt * 16 + (lane & 15);
            dst[j] = f2b(h_W[k * KK + n]);
        }
    } else if (c < 20992) {               // GT: nt 0..15 (n=256), ks 0..11 (k=384)
        int c4 = c - (1536 + 3072 + 4096);
        int lane = c4 & 63, ks = (c4 >> 6) % 12, nt = c4 / 768;
        ushort_t* dst = pack + (size_t)c * 8;
#pragma unroll
        for (int j = 0; j < 8; ++j) {
            int k = ks * 32 + ((lane >> 4) << 3) + j;
            int n = nt * 16 + (lane & 15);
            float v = (k < 128) ? g_n_W[k * EMB + n]
                   : (k < 256) ? g_same_W[(k - 128) * EMB + n]
                               : g_anti_W[(k - 256) * EMB + n];
            dst[j] = f2b(v);
        }
    } else if (c < 20992 + 192) {
        int i = c - 20992;
        b1cat[i] = (i < 64) ? w_n_b1[i] : (i < 128) ? w_same_b1[i - 64] : w_anti_b1[i - 128];
    } else if (c < 20992 + 192 + 384) {
        int i = c - 20992 - 192;
        b2cat[i] = (i < 128) ? w_n_b2[i] : (i < 256) ? w_same_b2[i - 128] : w_anti_b2[i - 256];
    } else if (c < 20992 + 192 + 384 + 256) {
        int i = c - 20992 - 192 - 384;
        gbsum[i] = g_n_b[i] + g_same_b[i] + g_anti_b[i];
    }
}

// ================= hx build (PERMUTED inner layout: pos(c) = (c&15)*8 + (c>>4)) =================
__global__ __launch_bounds__(256) void hx_nuc_perm(
    const float* __restrict__ nuc, ushort_t* __restrict__ hxb)
{
    int t = blockIdx.x * 256 + threadIdx.x;   // 0..131071
    int nn = t >> 4;                           // nuc row 0..8191
    int l  = t & 15;
    int node = (nn >> 2) * N_PART + (nn & 3);
    const float* src = nuc + (size_t)nn * KK;
    bf16x8 o;
#pragma unroll
    for (int j = 0; j < 8; ++j) o[j] = (short)f2b(src[l + 16 * j]);
    *(bf16x8*)(hxb + (size_t)node * KK + l * 8) = o;
}

__global__ __launch_bounds__(256) void hx_elec_mfma(
    const float* __restrict__ elec, const ushort_t* __restrict__ HWT,
    const float* __restrict__ h_b, ushort_t* __restrict__ hxb)
{
    int tid = threadIdx.x;
    int lane = tid & 63;
    int l15 = lane & 15, l4 = lane >> 4;
    int row0 = blockIdx.x * 64 + (tid >> 6) * 16;

    bf16x8 a[8];
    const float* ep = elec + (size_t)(row0 + l15) * EMB + l4 * 8;
#pragma unroll
    for (int ks = 0; ks < 8; ++ks) {
        float4 v0 = *(const float4*)(ep + ks * 32);
        float4 v1 = *(const float4*)(ep + ks * 32 + 4);
        bf16x8 av;
        av[0] = (short)f2b(v0.x); av[1] = (short)f2b(v0.y);
        av[2] = (short)f2b(v0.z); av[3] = (short)f2b(v0.w);
        av[4] = (short)f2b(v1.x); av[5] = (short)f2b(v1.y);
        av[6] = (short)f2b(v1.z); av[7] = (short)f2b(v1.w);
        a[ks] = av;
    }

    f32x4 acc[8];
#pragma unroll
    for (int nt = 0; nt < 8; ++nt) acc[nt] = (f32x4)(0.0f);
#pragma unroll
    for (int nt = 0; nt < 8; ++nt) {
#pragma unroll
        for (int ks = 0; ks < 8; ++ks) {
            bf16x8 b = *(const bf16x8*)(HWT + ((size_t)(nt * 8 + ks) * 64 + lane) * 8);
            acc[nt] = __builtin_amdgcn_mfma_f32_16x16x32_bf16(a[ks], b, acc[nt], 0, 0, 0);
        }
    }
#pragma unroll
    for (int nt = 0; nt < 8; ++nt) {
        int n = nt * 16 + l15;
        float hb = h_b[n];
#pragma unroll
        for (int r = 0; r < 4; ++r) {
            int erow = row0 + l4 * 4 + r;
            int node = (erow >> 4) * N_PART + N_NUC + (erow & 15);
            hxb[(size_t)node * KK + l15 * 8 + nt] = f2b(acc[nt][r] + hb);   // permuted
        }
    }
}

// ================= sort by (type, slot), segments padded to x16 =================
__global__ __launch_bounds__(256) void hist_kernel(
    const int* __restrict__ receivers, const int* __restrict__ e_type,
    int* __restrict__ cnt, int* __restrict__ rank)
{
    int e = blockIdx.x * 256 + threadIdx.x;
    if (e >= NE) return;
    int r = receivers[e];
    int bb = r / N_PART;
    int p = r - bb * N_PART;
    if (p >= N_NUC) {
        int et = e_type[e];
        int t = (et == 1) ? 0 : ((et == 3) ? 1 : 2);
        int key = t * N_ESLOT + (bb * N_ELEC + p - N_NUC);
        rank[e] = atomicAdd(&cnt[key], 1);
    } else {
        rank[e] = -1;
    }
}

// ---- hierarchical scan: local (96 blocks x 1024 elems) -> bsum (1 tiny); bsum folded at use ----
__global__ __launch_bounds__(256) void scan_local(int* __restrict__ cnt, int* __restrict__ bsum)
{
    __shared__ int sh[256];
    int t = threadIdx.x, bid = blockIdx.x;
    int base = bid * 1024 + t * 4;
    int4 v = *(const int4*)&cnt[base];
    int s = v.x + v.y + v.z + v.w;
    sh[t] = s;
    __syncthreads();
    for (int off = 1; off < 256; off <<= 1) {
        int add = (t >= off) ? sh[t - off] : 0;
        __syncthreads();
        sh[t] += add;
        __syncthreads();
    }
    int pre = sh[t] - s;
    int4 o;
    o.x = pre; o.y = pre + v.x; o.z = o.y + v.y; o.w = o.z + v.z;
    *(int4*)&cnt[base] = o;
    if (t == 255) bsum[bid] = sh[255];
}

__global__ __launch_bounds__(128) void scan_bsum(int* __restrict__ bsum, int* __restrict__ seg, int* __restrict__ cnt)
{
    __shared__ int sh[128];
    __shared__ int S1s, C2s, tots;
    int t = threadIdx.x;
    int v = (t < NSB) ? bsum[t] : 0;
    sh[t] = v;
    __syncthreads();
    for (int off = 1; off < 128; off <<= 1) {
        int add = (t >= off) ? sh[t - off] : 0;
        __syncthreads();
        sh[t] += add;
        __syncthreads();
    }
    int pre = sh[t] - v;      // exclusive prefix over block sums
    if (t == 31) S1s = sh[31];    // total of type-0 segment (blocks 0..31)
    if (t == 63) C2s = sh[63];    // total through type-1 segment
    if (t == NSB - 1) tots = sh[NSB - 1];
    __syncthreads();
    int S1 = S1s, C2 = C2s, tot = tots;
    int pad1 = (16 - (S1 & 15)) & 15;
    int pad2 = (16 - ((C2 + pad1) & 15)) & 15;
    if (t < NSB) {
        int add = ((t >= 32) ? pad1 : 0) + ((t >= 64) ? pad2 : 0);
        bsum[t] = pre + add;
    }
    if (t == NSB) bsum[NSB] = 0;   // so cnt[NKEY]+bsum[96] stays the padded total
    if (t == 0) {
        seg[0] = 0;
        seg[1] = S1 + pad1;
        seg[2] = C2 + pad1 + pad2;
        seg[3] = tot + pad1 + pad2;
        cnt[NKEY] = tot + pad1 + pad2;
    }
}

__global__ __launch_bounds__(256) void scatter_kernel(
    const int* __restrict__ receivers, const int* __restrict__ e_type,
    const int* __restrict__ cnt, const int* __restrict__ bsum,
    const int* __restrict__ rank, int* __restrict__ eidx)
{
    int e = blockIdx.x * 256 + threadIdx.x;
    if (e >= NE) return;
    int rk = rank[e];
    if (rk < 0) return;
    int r = receivers[e];
    int bb = r / N_PART;
    int p = r - bb * N_PART;
    int et = e_type[e];
    int t = (et == 1) ? 0 : ((et == 3) ? 1 : 2);
    int key = t * N_ESLOT + (bb * N_ELEC + p - N_NUC);
    eidx[cnt[key] + bsum[key >> 10] + rk] = e;
}

// ================= fused edge kernel: weh rows in sorted order =================
__global__ __launch_bounds__(256) void edge_fused(
    const float* __restrict__ dist, const int* __restrict__ senders,
    const int* __restrict__ eidx, const int* __restrict__ seg,
    const bf16x8* __restrict__ W1p, const float* __restrict__ b1cat,
    const bf16x8* __restrict__ W2p, const float* __restrict__ b2cat,
    const ushort_t* __restrict__ hxb, ushort_t* __restrict__ buf)
{
    __shared__ ushort_t tr[4][16 * TRS];
    int tid = threadIdx.x;
    int wave = tid >> 6, lane = tid & 63;
    int l15 = lane & 15, l4 = lane >> 4;
    int tile = blockIdx.x * 4 + wave;
    int total = seg[3];
    if (tile * 16 >= total) return;
    int t = (tile * 16 >= seg[1]) + (tile * 16 >= seg[2]);

    int e = eidx[tile * 16 + l15];
    int valid = (e >= 0) ? 1 : 0;
    int ec = valid ? e : 0;
    int snd = senders[ec];

    // A-frags from dist (gathered row, 64B/lane)
    bf16x8 a0, a1;
    {
        const float* dp = dist + (size_t)ec * DD + l4 * 8;
        float4 v0 = *(const float4*)(dp);
        float4 v1 = *(const float4*)(dp + 4);
        float4 v2 = *(const float4*)(dp + 32);
        float4 v3 = *(const float4*)(dp + 36);
        a0[0] = (short)f2b(v0.x); a0[1] = (short)f2b(v0.y);
        a0[2] = (short)f2b(v0.z); a0[3] = (short)f2b(v0.w);
        a0[4] = (short)f2b(v1.x); a0[5] = (short)f2b(v1.y);
        a0[6] = (short)f2b(v1.z); a0[7] = (short)f2b(v1.w);
        a1[0] = (short)f2b(v2.x); a1[1] = (short)f2b(v2.y);
        a1[2] = (short)f2b(v2.z); a1[3] = (short)f2b(v2.w);
        a1[4] = (short)f2b(v3.x); a1[5] = (short)f2b(v3.y);
        a1[6] = (short)f2b(v3.z); a1[7] = (short)f2b(v3.w);
    }

    // h1 = ssp(dist @ W1[t] + b1[t])  (8 MFMA)
    f32x4 ah[4];
#pragma unroll
    for (int q = 0; q < 4; ++q) ah[q] = (f32x4)(0.0f);
    const bf16x8* W1b = W1p + (size_t)(t * 4) * 2 * 64;
#pragma unroll
    for (int q = 0; q < 4; ++q) {
        bf16x8 b0 = W1b[(q * 2 + 0) * 64 + lane];
        bf16x8 b1v = W1b[(q * 2 + 1) * 64 + lane];
        ah[q] = __builtin_amdgcn_mfma_f32_16x16x32_bf16(a0, b0, ah[q], 0, 0, 0);
        ah[q] = __builtin_amdgcn_mfma_f32_16x16x32_bf16(a1, b1v, ah[q], 0, 0, 0);
    }

    // bias + ssp + per-wave LDS transpose (C-frag -> A-frag)
    ushort_t* trw = tr[wave];
#pragma unroll
    for (int q = 0; q < 4; ++q) {
        float bv = b1cat[t * 64 + q * 16 + l15];
#pragma unroll
        for (int r = 0; r < 4; ++r) {
            trw[(l4 * 4 + r) * TRS + q * 16 + l15] = f2b(ssp_f(ah[q][r] + bv));
        }
    }
    bf16x8 a2_0 = *(const bf16x8*)&trw[l15 * TRS + l4 * 8];
    bf16x8 a2_1 = *(const bf16x8*)&trw[l15 * TRS + 32 + l4 * 8];

    // weh = h1 @ W2[t] + b2[t]  (16 MFMA)
    f32x4 aw[8];
#pragma unroll
    for (int n = 0; n < 8; ++n) aw[n] = (f32x4)(0.0f);
    const bf16x8* W2b = W2p + (size_t)(t * 8) * 2 * 64;
#pragma unroll
    for (int n = 0; n < 8; ++n) {
        bf16x8 b0 = W2b[(n * 2 + 0) * 64 + lane];
        bf16x8 b1v = W2b[(n * 2 + 1) * 64 + lane];
        aw[n] = __builtin_amdgcn_mfma_f32_16x16x32_bf16(a2_0, b0, aw[n], 0, 0, 0);
        aw[n] = __builtin_amdgcn_mfma_f32_16x16x32_bf16(a2_1, b1v, aw[n], 0, 0, 0);
    }
    float bw[8];
#pragma unroll
    for (int n = 0; n < 8; ++n) bw[n] = b2cat[t * KK + n * 16 + l15];

    // epilogue: * hx[sender] (permuted b128 gather), store permuted b128 (zeros for pads)
#pragma unroll
    for (int r = 0; r < 4; ++r) {
        int m = l4 * 4 + r;
        int sdr = __shfl(snd, m);
        int vr  = __shfl(valid, m);
        bf16x8 hv = *(const bf16x8*)(hxb + (size_t)sdr * KK + l15 * 8);
        bf16x8 o;
#pragma unroll
        for (int n = 0; n < 8; ++n) {
            float w = aw[n][r] + bw[n];
            float val = vr ? w * b2f((unsigned short)hv[n]) : 0.0f;
            o[n] = (short)f2b(val);
        }
        *(bf16x8*)(buf + (size_t)(tile * 16 + m) * KK + l15 * 8) = o;
    }
}

// ================= zgather: contiguous bucket ranges, un-permute on write =================
__global__ __launch_bounds__(256) void zgather2(
    const int* __restrict__ cnt, const int* __restrict__ bsum,
    const ushort_t* __restrict__ buf, ushort_t* __restrict__ Zb)
{
    int tid = threadIdx.x;
    int lane = tid & 63;
    int wid = blockIdx.x * 4 + (tid >> 6);
    int nw = gridDim.x * 4;

    int p0 = 2 * lane, p1 = 2 * lane + 1;
    int c0 = (p0 >> 3) + (p0 & 7) * 16;
    int c1 = (p1 >> 3) + (p1 & 7) * 16;

    for (int slot = wid; slot < N_ESLOT; slot += nw) {
#pragma unroll 3
        for (int t = 0; t < 3; ++t) {
            int idx = t * N_ESLOT + slot;
            int lo = cnt[idx] + bsum[idx >> 10];
            int hi = cnt[idx + 1] + bsum[(idx + 1) >> 10];
            float acc0 = 0.0f, acc1 = 0.0f;
            for (int i = lo; i < hi; ++i) {
                unsigned int v = *(const unsigned int*)(buf + (size_t)i * KK + 2 * lane);
                acc0 += b2f((unsigned short)(v & 0xffff));
                acc1 += b2f((unsigned short)(v >> 16));
            }
            Zb[(size_t)slot * 384 + t * KK + c0] = f2b(acc0);
            Zb[(size_t)slot * 384 + t * KK + c1] = f2b(acc1);
        }
    }
}

// ================= gout: out = elec + Zb @ GT + gb (MFMA, swapped operands) =================
// D = mfma(GT_frag, Zb_frag) -> D[n][row]: lane owns 4 consecutive n for one out row.
// block: 512 threads = 8 waves; 64 rows x 256 cols (4 row-waves x 2 col-halves).
__global__ __launch_bounds__(512, 4) void gout_mfma(
    const ushort_t* __restrict__ Zb, const float* __restrict__ elec,
    const ushort_t* __restrict__ GT, const float* __restrict__ gbsum,
    float* __restrict__ out)
{
    int tid = threadIdx.x;
    int lane = tid & 63;
    int l15 = lane & 15, l4 = lane >> 4;
    int wave = tid >> 6;
    int rw = wave & 3;            // row-wave
    int ch = wave >> 2;           // col half
    int row0 = blockIdx.x * 64 + rw * 16;
    int ntb = ch * 8;

    // B-frags: Zb rows (held across all nt)
    bf16x8 zb[12];
    const ushort_t* zp = Zb + (size_t)(row0 + l15) * 384 + l4 * 8;
#pragma unroll
    for (int ks = 0; ks < 12; ++ks)
        zb[ks] = *(const bf16x8*)(zp + ks * 32);

    f32x4 acc[8];
#pragma unroll
    for (int nt = 0; nt < 8; ++nt) acc[nt] = (f32x4)(0.0f);
#pragma unroll
    for (int nt = 0; nt < 8; ++nt) {
#pragma unroll
        for (int ks = 0; ks < 12; ++ks) {
            bf16x8 g = *(const bf16x8*)(GT + ((size_t)((ntb + nt) * 12 + ks) * 64 + lane) * 8);
            acc[nt] = __builtin_amdgcn_mfma_f32_16x16x32_bf16(g, zb[ks], acc[nt], 0, 0, 0);
        }
    }

    // epilogue: float4 RMW; lane owns n0..n0+3 of row row0+l15
#pragma unroll
    for (int nt = 0; nt < 8; ++nt) {
        int n0 = (ntb + nt) * 16 + l4 * 4;
        float4 gbv = *(const float4*)(gbsum + n0);
        size_t o = (size_t)(row0 + l15) * EMB + n0;
        float4 ev = *(const float4*)(elec + o);
        float4 res;
        res.x = ev.x + acc[nt][0] + gbv.x;
        res.y = ev.y + acc[nt][1] + gbv.y;
        res.z = ev.z + acc[nt][2] + gbv.z;
        res.w = ev.w + acc[nt][3] + gbv.w;
        *(float4*)(out + o) = res;
    }
}

extern "C" void kernel_launch(void* const* d_in, const int* in_sizes, int n_in,
                              void* d_out, int out_size, void* d_ws, size_t ws_size,
                              hipStream_t stream) {
    const float* nuc       = (const float*)d_in[0];
    const float* elec      = (const float*)d_in[1];
    const float* dist      = (const float*)d_in[2];
    const int*   e_type    = (const int*)d_in[3];
    const int*   senders   = (const int*)d_in[4];
    const int*   receivers = (const int*)d_in[5];
    const float* w_same_W1 = (const float*)d_in[6];
    const float* w_same_b1 = (const float*)d_in[7];
    const float* w_same_W2 = (const float*)d_in[8];
    const float* w_same_b2 = (const float*)d_in[9];
    const float* w_anti_W1 = (const float*)d_in[10];
    const float* w_anti_b1 = (const float*)d_in[11];
    const float* w_anti_W2 = (const float*)d_in[12];
    const float* w_anti_b2 = (const float*)d_in[13];
    const float* w_n_W1    = (const float*)d_in[14];
    const float* w_n_b1    = (const float*)d_in[15];
    const float* w_n_W2    = (const float*)d_in[16];
    const float* w_n_b2    = (const float*)d_in[17];
    const float* h_W       = (const float*)d_in[18];
    const float* h_b       = (const float*)d_in[19];
    const float* g_same_W  = (const float*)d_in[20];
    const float* g_same_b  = (const float*)d_in[21];
    const float* g_anti_W  = (const float*)d_in[22];
    const float* g_anti_b  = (const float*)d_in[23];
    const float* g_n_W     = (const float*)d_in[24];
    const float* g_n_b     = (const float*)d_in[25];

    float* out = (float*)d_out;

    // ---- workspace layout ----
    char* w = (char*)d_ws;
    ushort_t* pack = (ushort_t*)w;                         // 20992*16 = 335,872 B
    size_t off = 20992 * 16;
    float* b1cat = (float*)(w + off);  off += 192 * 4;
    float* b2cat = (float*)(w + off);  off += 384 * 4;
    float* gbsum = (float*)(w + off);  off += 256 * 4;
    int*   seg   = (int*)(w + off);    off += 4 * 4;
    off = (off + 255) & ~(size_t)255;
    int*   bsum  = (int*)(w + off);    off += 128 * 4;
    off = (off + 255) & ~(size_t)255;
    ushort_t* hxb = (ushort_t*)(w + off);  off += (size_t)N_NODES * KK * 2;        // 10.5 MB
    ushort_t* buf = (ushort_t*)(w + off);  off += (size_t)(NE + 64) * KK * 2;      // 78.7 MB
    ushort_t* Zb  = (ushort_t*)(w + off);  off += (size_t)N_ESLOT * 384 * 2;       // 25.2 MB
    int* cnt  = (int*)(w + off);  off += (size_t)(NKEY + 1) * 4 + 252; off &= ~(size_t)255;
    int* rank = (int*)(w + off);  off += (size_t)NE * 4;
    int* eidx = (int*)(w + off);  off += (size_t)(NE + 64) * 4;

    const ushort_t* W1pack = pack;
    const ushort_t* W2pack = pack + (size_t)1536 * 8;
    const ushort_t* HWT    = pack + (size_t)(1536 + 3072) * 8;
    const ushort_t* GT     = pack + (size_t)(1536 + 3072 + 4096) * 8;

    hipMemsetAsync(cnt, 0, (size_t)(NKEY + 1) * 4, stream);
    hipMemsetAsync(eidx, 0xFF, (size_t)(NE + 64) * 4, stream);   // -1 pads

    prep_kernel<<<86, 256, 0, stream>>>(
        w_n_W1, w_same_W1, w_anti_W1, w_n_W2, w_same_W2, w_anti_W2,
        h_W, g_n_W, g_same_W, g_anti_W,
        w_n_b1, w_same_b1, w_anti_b1, w_n_b2, w_same_b2, w_anti_b2,
        g_n_b, g_same_b, g_anti_b,
        (ushort_t*)pack, b1cat, b2cat, gbsum);

    hx_nuc_perm<<<512, 256, 0, stream>>>(nuc, hxb);
    hx_elec_mfma<<<N_ESLOT / 64, 256, 0, stream>>>(elec, HWT, h_b, hxb);

    hist_kernel<<<NE / 256, 256, 0, stream>>>(receivers, e_type, cnt, rank);
    scan_local<<<NSB, 256, 0, stream>>>(cnt, bsum);
    scan_bsum<<<1, 128, 0, stream>>>(bsum, seg, cnt);
    scatter_kernel<<<NE / 256, 256, 0, stream>>>(receivers, e_type, cnt, bsum, rank, eidx);

    edge_fused<<<(NE / 16 + 3 + 3) / 4 + 1, 256, 0, stream>>>(dist, senders, eidx, seg,
        (const bf16x8*)W1pack, b1cat, (const bf16x8*)W2pack, b2cat, hxb, buf);

    zgather2<<<2048, 256, 0, stream>>>(cnt, bsum, buf, Zb);

    gout_mfma<<<N_ESLOT / 64, 512, 0, stream>>>(Zb, elec, GT, gbsum, out);
}

// Round 7
// 149.729 us; speedup vs baseline: 6.0794x; 1.1046x over previous
//
#include <hip/hip_runtime.h>
#include <hip/hip_bf16.h>
#include <math.h>

#define NB      2048
#define N_NUC   4
#define N_ELEC  16
#define N_PART  20
#define N_NODES (NB * N_PART)     // 40960
#define NE      307200
#define DD      64
#define KK      128
#define EMB     256
#define N_ESLOT (NB * N_ELEC)     // 32768
#define NKEY    (N_ESLOT * 3)     // 98304
#define NSB     96                // scan blocks (NKEY/1024)
#define TRS     76                // LDS transpose row stride (ushorts)

typedef __attribute__((ext_vector_type(8))) short bf16x8;
typedef __attribute__((ext_vector_type(4))) float f32x4;
typedef unsigned short ushort_t;

__device__ __forceinline__ unsigned short f2b(float f) {   // RTNE (prep only)
    union { float f; unsigned int u; } v; v.f = f;
    unsigned int r = (v.u + 0x7fffu + ((v.u >> 16) & 1u)) >> 16;
    return (unsigned short)r;
}
__device__ __forceinline__ unsigned short f2b_hup(float f) { // round-half-up (cheap)
    union { float f; unsigned int u; } v; v.f = f;
    return (unsigned short)((v.u + 0x8000u) >> 16);
}
__device__ __forceinline__ float b2f(unsigned short u) {
    union { unsigned int u; float f; } v; v.u = ((unsigned int)u) << 16;
    return v.f;
}
__device__ __forceinline__ float fexp2(float x) {
    float r; asm("v_exp_f32 %0, %1" : "=v"(r) : "v"(x)); return r;
}
__device__ __forceinline__ float flog2(float x) {
    float r; asm("v_log_f32 %0, %1" : "=v"(r) : "v"(x)); return r;
}
// softplus(x) - ln2 = max(x,0) + ln2*(log2(1+2^(-|x|*log2e)) - 1)
__device__ __forceinline__ float ssp_fast(float x) {
    float t = fexp2(fabsf(x) * -1.4426950408889634f);
    float l = flog2(1.0f + t);
    return fmaxf(x, 0.0f) + 0.6931471805599453f * (l - 1.0f);
}
__device__ __forceinline__ unsigned int cvtpk(float lo, float hi) {
    unsigned int r;
    asm("v_cvt_pk_bf16_f32 %0, %1, %2" : "=v"(r) : "v"(lo), "v"(hi));
    return r;
}

// ================= prep: pack weights into MFMA-fragment layout (bf16) =================
__global__ __launch_bounds__(256) void prep_kernel(
    const float* __restrict__ w_n_W1, const float* __restrict__ w_same_W1, const float* __restrict__ w_anti_W1,
    const float* __restrict__ w_n_W2, const float* __restrict__ w_same_W2, const float* __restrict__ w_anti_W2,
    const float* __restrict__ h_W,
    const float* __restrict__ g_n_W, const float* __restrict__ g_same_W, const float* __restrict__ g_anti_W,
    const float* __restrict__ w_n_b1, const float* __restrict__ w_same_b1, const float* __restrict__ w_anti_b1,
    const float* __restrict__ w_n_b2, const float* __restrict__ w_same_b2, const float* __restrict__ w_anti_b2,
    const float* __restrict__ g_n_b, const float* __restrict__ g_same_b, const float* __restrict__ g_anti_b,
    ushort_t* __restrict__ pack, float* __restrict__ b1cat, float* __restrict__ b2cat,
    float* __restrict__ gbsum)
{
    int c = blockIdx.x * 256 + threadIdx.x;
    if (c < 1536) {                       // W1pack: nt 0..11 (n=192), ks 0..1
        int lane = c & 63, ks = (c >> 6) & 1, nt = c >> 7;
        ushort_t* dst = pack + (size_t)c * 8;
#pragma unroll
        for (int j = 0; j < 8; ++j) {
            int k = ks * 32 + ((lane >> 4) << 3) + j;
            int n = nt * 16 + (lane & 15);
            float v = (n < 64) ? w_n_W1[k * 64 + n]
                   : (n < 128) ? w_same_W1[k * 64 + n - 64]
                               : w_anti_W1[k * 64 + n - 128];
            dst[j] = f2b(v);
        }
    } else if (c < 1536 + 3072) {         // W2pack: nt 0..23 (n=384), ks 0..1
        int c2 = c - 1536;
        int lane = c2 & 63, ks = (c2 >> 6) & 1, nt = c2 >> 7;
        ushort_t* dst = pack + (size_t)c * 8;
#pragma unroll
        for (int j = 0; j < 8; ++j) {
            int k = ks * 32 + ((lane >> 4) << 3) + j;
            int n = nt * 16 + (lane & 15);
            float v = (n < 128) ? w_n_W2[k * KK + n]
                   : (n < 256) ? w_same_W2[k * KK + n - 128]
                               : w_anti_W2[k * KK + n - 256];
            dst[j] = f2b(v);
        }
    } else if (c < 1536 + 3072 + 4096) {  // HWT: nt 0..7 (n=128), ks 0..7
        int c3 = c - (1536 + 3072);
        int lane = c3 & 63, ks = (c3 >> 6) & 7, nt = c3 >> 9;
        ushort_t* dst = pack + (size_t)c * 8;
#pragma unroll
        for (int j = 0; j < 8; ++j) {
            int k = ks * 32 + ((lane >> 4) << 3) + j;
            int n = nt * 16 + (lane & 15);
            dst[j] = f2b(h_W[k * KK + n]);
        }
    } else if (c < 20992) {               // GT: nt 0..15 (n=256), ks 0..11 (k=384)
        int c4 = c - (1536 + 3072 + 4096);
        int lane = c4 & 63, ks = (c4 >> 6) % 12, nt = c4 / 768;
        ushort_t* dst = pack + (size_t)c * 8;
#pragma unroll
        for (int j = 0; j < 8; ++j) {
            int k = ks * 32 + ((lane >> 4) << 3) + j;
            int n = nt * 16 + (lane & 15);
            float v = (k < 128) ? g_n_W[k * EMB + n]
                   : (k < 256) ? g_same_W[(k - 128) * EMB + n]
                               : g_anti_W[(k - 256) * EMB + n];
            dst[j] = f2b(v);
        }
    } else if (c < 20992 + 192) {
        int i = c - 20992;
        b1cat[i] = (i < 64) ? w_n_b1[i] : (i < 128) ? w_same_b1[i - 64] : w_anti_b1[i - 128];
    } else if (c < 20992 + 192 + 384) {
        int i = c - 20992 - 192;
        b2cat[i] = (i < 128) ? w_n_b2[i] : (i < 256) ? w_same_b2[i - 128] : w_anti_b2[i - 256];
    } else if (c < 20992 + 192 + 384 + 256) {
        int i = c - 20992 - 192 - 384;
        gbsum[i] = g_n_b[i] + g_same_b[i] + g_anti_b[i];
    }
}

// ================= hx build (PERMUTED inner layout: pos(c) = (c&15)*8 + (c>>4)) =================
__global__ __launch_bounds__(256) void hx_nuc_perm(
    const float* __restrict__ nuc, ushort_t* __restrict__ hxb)
{
    int t = blockIdx.x * 256 + threadIdx.x;   // 0..131071
    int nn = t >> 4;                           // nuc row 0..8191
    int l  = t & 15;
    int node = (nn >> 2) * N_PART + (nn & 3);
    const float* src = nuc + (size_t)nn * KK;
    bf16x8 o;
#pragma unroll
    for (int j = 0; j < 8; ++j) o[j] = (short)f2b(src[l + 16 * j]);
    *(bf16x8*)(hxb + (size_t)node * KK + l * 8) = o;
}

__global__ __launch_bounds__(256) void hx_elec_mfma(
    const float* __restrict__ elec, const ushort_t* __restrict__ HWT,
    const float* __restrict__ h_b, ushort_t* __restrict__ hxb)
{
    int tid = threadIdx.x;
    int lane = tid & 63;
    int l15 = lane & 15, l4 = lane >> 4;
    int row0 = blockIdx.x * 64 + (tid >> 6) * 16;

    union { bf16x8 v; unsigned int u[4]; } a[8];
    const float* ep = elec + (size_t)(row0 + l15) * EMB + l4 * 8;
#pragma unroll
    for (int ks = 0; ks < 8; ++ks) {
        float4 v0 = *(const float4*)(ep + ks * 32);
        float4 v1 = *(const float4*)(ep + ks * 32 + 4);
        a[ks].u[0] = cvtpk(v0.x, v0.y); a[ks].u[1] = cvtpk(v0.z, v0.w);
        a[ks].u[2] = cvtpk(v1.x, v1.y); a[ks].u[3] = cvtpk(v1.z, v1.w);
    }

    f32x4 acc[8];
#pragma unroll
    for (int nt = 0; nt < 8; ++nt) acc[nt] = (f32x4)(h_b[nt * 16 + l15]);  // bias in acc
#pragma unroll
    for (int nt = 0; nt < 8; ++nt) {
#pragma unroll
        for (int ks = 0; ks < 8; ++ks) {
            bf16x8 b = *(const bf16x8*)(HWT + ((size_t)(nt * 8 + ks) * 64 + lane) * 8);
            acc[nt] = __builtin_amdgcn_mfma_f32_16x16x32_bf16(a[ks].v, b, acc[nt], 0, 0, 0);
        }
    }
#pragma unroll
    for (int nt = 0; nt < 8; ++nt) {
#pragma unroll
        for (int r = 0; r < 4; ++r) {
            int erow = row0 + l4 * 4 + r;
            int node = (erow >> 4) * N_PART + N_NUC + (erow & 15);
            hxb[(size_t)node * KK + l15 * 8 + nt] = f2b_hup(acc[nt][r]);   // permuted
        }
    }
}

// ================= sort by (type, slot), segments padded to x16 =================
__global__ __launch_bounds__(256) void hist_kernel(
    const int* __restrict__ receivers, const int* __restrict__ e_type,
    int* __restrict__ cnt, int* __restrict__ rank)
{
    int e = blockIdx.x * 256 + threadIdx.x;
    if (e >= NE) return;
    int r = receivers[e];
    int bb = r / N_PART;
    int p = r - bb * N_PART;
    if (p >= N_NUC) {
        int et = e_type[e];
        int t = (et == 1) ? 0 : ((et == 3) ? 1 : 2);
        int key = t * N_ESLOT + (bb * N_ELEC + p - N_NUC);
        rank[e] = atomicAdd(&cnt[key], 1);
    } else {
        rank[e] = -1;
    }
}

// ---- hierarchical scan: local (96 blocks x 1024 elems) -> bsum (1 tiny); bsum folded at use ----
__global__ __launch_bounds__(256) void scan_local(int* __restrict__ cnt, int* __restrict__ bsum)
{
    __shared__ int sh[256];
    int t = threadIdx.x, bid = blockIdx.x;
    int base = bid * 1024 + t * 4;
    int4 v = *(const int4*)&cnt[base];
    int s = v.x + v.y + v.z + v.w;
    sh[t] = s;
    __syncthreads();
    for (int off = 1; off < 256; off <<= 1) {
        int add = (t >= off) ? sh[t - off] : 0;
        __syncthreads();
        sh[t] += add;
        __syncthreads();
    }
    int pre = sh[t] - s;
    int4 o;
    o.x = pre; o.y = pre + v.x; o.z = o.y + v.y; o.w = o.z + v.z;
    *(int4*)&cnt[base] = o;
    if (t == 255) bsum[bid] = sh[255];
}

__global__ __launch_bounds__(128) void scan_bsum(int* __restrict__ bsum, int* __restrict__ seg, int* __restrict__ cnt)
{
    __shared__ int sh[128];
    __shared__ int S1s, C2s, tots;
    int t = threadIdx.x;
    int v = (t < NSB) ? bsum[t] : 0;
    sh[t] = v;
    __syncthreads();
    for (int off = 1; off < 128; off <<= 1) {
        int add = (t >= off) ? sh[t - off] : 0;
        __syncthreads();
        sh[t] += add;
        __syncthreads();
    }
    int pre = sh[t] - v;      // exclusive prefix over block sums
    if (t == 31) S1s = sh[31];    // total of type-0 segment (blocks 0..31)
    if (t == 63) C2s = sh[63];    // total through type-1 segment
    if (t == NSB - 1) tots = sh[NSB - 1];
    __syncthreads();
    int S1 = S1s, C2 = C2s, tot = tots;
    int pad1 = (16 - (S1 & 15)) & 15;
    int pad2 = (16 - ((C2 + pad1) & 15)) & 15;
    if (t < NSB) {
        int add = ((t >= 32) ? pad1 : 0) + ((t >= 64) ? pad2 : 0);
        bsum[t] = pre + add;
    }
    if (t == NSB) bsum[NSB] = 0;   // so cnt[NKEY]+bsum[96] stays the padded total
    if (t == 0) {
        seg[0] = 0;
        seg[1] = S1 + pad1;
        seg[2] = C2 + pad1 + pad2;
        seg[3] = tot + pad1 + pad2;
        cnt[NKEY] = tot + pad1 + pad2;
    }
}

__global__ __launch_bounds__(256) void scatter_kernel(
    const int* __restrict__ receivers, const int* __restrict__ e_type,
    const int* __restrict__ cnt, const int* __restrict__ bsum,
    const int* __restrict__ rank, int* __restrict__ eidx)
{
    int e = blockIdx.x * 256 + threadIdx.x;
    if (e >= NE) return;
    int rk = rank[e];
    if (rk < 0) return;
    int r = receivers[e];
    int bb = r / N_PART;
    int p = r - bb * N_PART;
    int et = e_type[e];
    int t = (et == 1) ? 0 : ((et == 3) ? 1 : 2);
    int key = t * N_ESLOT + (bb * N_ELEC + p - N_NUC);
    eidx[cnt[key] + bsum[key >> 10] + rk] = e;
}

// ================= fused edge kernel: weh rows in sorted order (grid-stride) =================
__global__ __launch_bounds__(256) void edge_fused(
    const float* __restrict__ dist, const int* __restrict__ senders,
    const int* __restrict__ eidx, const int* __restrict__ seg,
    const bf16x8* __restrict__ W1p, const float* __restrict__ b1cat,
    const bf16x8* __restrict__ W2p, const float* __restrict__ b2cat,
    const ushort_t* __restrict__ hxb, ushort_t* __restrict__ buf)
{
    __shared__ ushort_t tr[4][16 * TRS];
    int tid = threadIdx.x;
    int wave = tid >> 6, lane = tid & 63;
    int l15 = lane & 15, l4 = lane >> 4;
    int total = seg[3];
    int s1 = seg[1], s2 = seg[2];
    ushort_t* trw = tr[wave];
    int nw = gridDim.x * 4;

    for (int tile = blockIdx.x * 4 + wave; tile * 16 < total; tile += nw) {
        int t = (tile * 16 >= s1) + (tile * 16 >= s2);
        int e = eidx[tile * 16 + l15];
        int valid = (e >= 0) ? 1 : 0;
        int ec = valid ? e : 0;
        int snd = senders[ec];

        // A-frags from dist (gathered row, 64B/lane), packed converts
        union { bf16x8 v; unsigned int u[4]; } A0, A1;
        {
            const float* dp = dist + (size_t)ec * DD + l4 * 8;
            float4 v0 = *(const float4*)(dp);
            float4 v1 = *(const float4*)(dp + 4);
            float4 v2 = *(const float4*)(dp + 32);
            float4 v3 = *(const float4*)(dp + 36);
            A0.u[0] = cvtpk(v0.x, v0.y); A0.u[1] = cvtpk(v0.z, v0.w);
            A0.u[2] = cvtpk(v1.x, v1.y); A0.u[3] = cvtpk(v1.z, v1.w);
            A1.u[0] = cvtpk(v2.x, v2.y); A1.u[1] = cvtpk(v2.z, v2.w);
            A1.u[2] = cvtpk(v3.x, v3.y); A1.u[3] = cvtpk(v3.z, v3.w);
        }

        // h1 = ssp(dist @ W1[t] + b1[t])  (8 MFMA, bias in acc)
        f32x4 ah[4];
#pragma unroll
        for (int q = 0; q < 4; ++q) ah[q] = (f32x4)(b1cat[t * 64 + q * 16 + l15]);
        const bf16x8* W1b = W1p + (size_t)(t * 4) * 2 * 64;
#pragma unroll
        for (int q = 0; q < 4; ++q) {
            bf16x8 b0 = W1b[(q * 2 + 0) * 64 + lane];
            bf16x8 b1v = W1b[(q * 2 + 1) * 64 + lane];
            ah[q] = __builtin_amdgcn_mfma_f32_16x16x32_bf16(A0.v, b0, ah[q], 0, 0, 0);
            ah[q] = __builtin_amdgcn_mfma_f32_16x16x32_bf16(A1.v, b1v, ah[q], 0, 0, 0);
        }

        // ssp + per-wave LDS transpose (C-frag -> A-frag)
#pragma unroll
        for (int q = 0; q < 4; ++q) {
#pragma unroll
            for (int r = 0; r < 4; ++r) {
                trw[(l4 * 4 + r) * TRS + q * 16 + l15] = f2b_hup(ssp_fast(ah[q][r]));
            }
        }
        bf16x8 a2_0 = *(const bf16x8*)&trw[l15 * TRS + l4 * 8];
        bf16x8 a2_1 = *(const bf16x8*)&trw[l15 * TRS + 32 + l4 * 8];

        // weh = h1 @ W2[t] + b2[t]  (16 MFMA, bias in acc)
        f32x4 aw[8];
#pragma unroll
        for (int n = 0; n < 8; ++n) aw[n] = (f32x4)(b2cat[t * KK + n * 16 + l15]);
        const bf16x8* W2b = W2p + (size_t)(t * 8) * 2 * 64;
#pragma unroll
        for (int n = 0; n < 8; ++n) {
            bf16x8 b0 = W2b[(n * 2 + 0) * 64 + lane];
            bf16x8 b1v = W2b[(n * 2 + 1) * 64 + lane];
            aw[n] = __builtin_amdgcn_mfma_f32_16x16x32_bf16(a2_0, b0, aw[n], 0, 0, 0);
            aw[n] = __builtin_amdgcn_mfma_f32_16x16x32_bf16(a2_1, b1v, aw[n], 0, 0, 0);
        }

        // epilogue: * hx[sender] (permuted b128 gather), packed cvt, store b128 (zeros for pads)
#pragma unroll
        for (int r = 0; r < 4; ++r) {
            int m = l4 * 4 + r;
            int sdr = __shfl(snd, m);
            int vr  = __shfl(valid, m);
            bf16x8 hv = *(const bf16x8*)(hxb + (size_t)sdr * KK + l15 * 8);
            float p0 = aw[0][r] * b2f((unsigned short)hv[0]);
            float p1 = aw[1][r] * b2f((unsigned short)hv[1]);
            float p2 = aw[2][r] * b2f((unsigned short)hv[2]);
            float p3 = aw[3][r] * b2f((unsigned short)hv[3]);
            float p4 = aw[4][r] * b2f((unsigned short)hv[4]);
            float p5 = aw[5][r] * b2f((unsigned short)hv[5]);
            float p6 = aw[6][r] * b2f((unsigned short)hv[6]);
            float p7 = aw[7][r] * b2f((unsigned short)hv[7]);
            union { bf16x8 v; unsigned int u[4]; } O;
            O.u[0] = vr ? cvtpk(p0, p1) : 0u;
            O.u[1] = vr ? cvtpk(p2, p3) : 0u;
            O.u[2] = vr ? cvtpk(p4, p5) : 0u;
            O.u[3] = vr ? cvtpk(p6, p7) : 0u;
            *(bf16x8*)(buf + (size_t)(tile * 16 + m) * KK + l15 * 8) = O.v;
        }
    }
}

// ================= zgather: contiguous bucket ranges, un-permute on write =================
__global__ __launch_bounds__(256) void zgather2(
    const int* __restrict__ cnt, const int* __restrict__ bsum,
    const ushort_t* __restrict__ buf, ushort_t* __restrict__ Zb)
{
    int tid = threadIdx.x;
    int lane = tid & 63;
    int wid = blockIdx.x * 4 + (tid >> 6);
    int nw = gridDim.x * 4;

    int p0 = 2 * lane, p1 = 2 * lane + 1;
    int c0 = (p0 >> 3) + (p0 & 7) * 16;
    int c1 = (p1 >> 3) + (p1 & 7) * 16;

    for (int slot = wid; slot < N_ESLOT; slot += nw) {
#pragma unroll 3
        for (int t = 0; t < 3; ++t) {
            int idx = t * N_ESLOT + slot;
            int lo = cnt[idx] + bsum[idx >> 10];
            int hi = cnt[idx + 1] + bsum[(idx + 1) >> 10];
            float acc0 = 0.0f, acc1 = 0.0f;
            for (int i = lo; i < hi; ++i) {
                unsigned int v = *(const unsigned int*)(buf + (size_t)i * KK + 2 * lane);
                acc0 += b2f((unsigned short)(v & 0xffff));
                acc1 += b2f((unsigned short)(v >> 16));
            }
            Zb[(size_t)slot * 384 + t * KK + c0] = f2b_hup(acc0);
            Zb[(size_t)slot * 384 + t * KK + c1] = f2b_hup(acc1);
        }
    }
}

// ================= gout: out = elec + Zb @ GT + gb (MFMA, swapped operands) =================
__global__ __launch_bounds__(512, 4) void gout_mfma(
    const ushort_t* __restrict__ Zb, const float* __restrict__ elec,
    const ushort_t* __restrict__ GT, const float* __restrict__ gbsum,
    float* __restrict__ out)
{
    int tid = threadIdx.x;
    int lane = tid & 63;
    int l15 = lane & 15, l4 = lane >> 4;
    int wave = tid >> 6;
    int rw = wave & 3;            // row-wave
    int ch = wave >> 2;           // col half
    int row0 = blockIdx.x * 64 + rw * 16;
    int ntb = ch * 8;

    // B-frags: Zb rows (held across all nt)
    bf16x8 zb[12];
    const ushort_t* zp = Zb + (size_t)(row0 + l15) * 384 + l4 * 8;
#pragma unroll
    for (int ks = 0; ks < 12; ++ks)
        zb[ks] = *(const bf16x8*)(zp + ks * 32);

    f32x4 acc[8];
#pragma unroll
    for (int nt = 0; nt < 8; ++nt) acc[nt] = (f32x4)(0.0f);
#pragma unroll
    for (int nt = 0; nt < 8; ++nt) {
#pragma unroll
        for (int ks = 0; ks < 12; ++ks) {
            bf16x8 g = *(const bf16x8*)(GT + ((size_t)((ntb + nt) * 12 + ks) * 64 + lane) * 8);
            acc[nt] = __builtin_amdgcn_mfma_f32_16x16x32_bf16(g, zb[ks], acc[nt], 0, 0, 0);
        }
    }

    // epilogue: float4 RMW; lane owns n0..n0+3 of row row0+l15
#pragma unroll
    for (int nt = 0; nt < 8; ++nt) {
        int n0 = (ntb + nt) * 16 + l4 * 4;
        float4 gbv = *(const float4*)(gbsum + n0);
        size_t o = (size_t)(row0 + l15) * EMB + n0;
        float4 ev = *(const float4*)(elec + o);
        float4 res;
        res.x = ev.x + acc[nt][0] + gbv.x;
        res.y = ev.y + acc[nt][1] + gbv.y;
        res.z = ev.z + acc[nt][2] + gbv.z;
        res.w = ev.w + acc[nt][3] + gbv.w;
        *(float4*)(out + o) = res;
    }
}

extern "C" void kernel_launch(void* const* d_in, const int* in_sizes, int n_in,
                              void* d_out, int out_size, void* d_ws, size_t ws_size,
                              hipStream_t stream) {
    const float* nuc       = (const float*)d_in[0];
    const float* elec      = (const float*)d_in[1];
    const float* dist      = (const float*)d_in[2];
    const int*   e_type    = (const int*)d_in[3];
    const int*   senders   = (const int*)d_in[4];
    const int*   receivers = (const int*)d_in[5];
    const float* w_same_W1 = (const float*)d_in[6];
    const float* w_same_b1 = (const float*)d_in[7];
    const float* w_same_W2 = (const float*)d_in[8];
    const float* w_same_b2 = (const float*)d_in[9];
    const float* w_anti_W1 = (const float*)d_in[10];
    const float* w_anti_b1 = (const float*)d_in[11];
    const float* w_anti_W2 = (const float*)d_in[12];
    const float* w_anti_b2 = (const float*)d_in[13];
    const float* w_n_W1    = (const float*)d_in[14];
    const float* w_n_b1    = (const float*)d_in[15];
    const float* w_n_W2    = (const float*)d_in[16];
    const float* w_n_b2    = (const float*)d_in[17];
    const float* h_W       = (const float*)d_in[18];
    const float* h_b       = (const float*)d_in[19];
    const float* g_same_W  = (const float*)d_in[20];
    const float* g_same_b  = (const float*)d_in[21];
    const float* g_anti_W  = (const float*)d_in[22];
    const float* g_anti_b  = (const float*)d_in[23];
    const float* g_n_W     = (const float*)d_in[24];
    const float* g_n_b     = (const float*)d_in[25];

    float* out = (float*)d_out;

    // ---- workspace layout ----
    char* w = (char*)d_ws;
    ushort_t* pack = (ushort_t*)w;                         // 20992*16 = 335,872 B
    size_t off = 20992 * 16;
    float* b1cat = (float*)(w + off);  off += 192 * 4;
    float* b2cat = (float*)(w + off);  off += 384 * 4;
    float* gbsum = (float*)(w + off);  off += 256 * 4;
    int*   seg   = (int*)(w + off);    off += 4 * 4;
    off = (off + 255) & ~(size_t)255;
    int*   bsum  = (int*)(w + off);    off += 128 * 4;
    off = (off + 255) & ~(size_t)255;
    ushort_t* hxb = (ushort_t*)(w + off);  off += (size_t)N_NODES * KK * 2;        // 10.5 MB
    ushort_t* buf = (ushort_t*)(w + off);  off += (size_t)(NE + 64) * KK * 2;      // 78.7 MB
    ushort_t* Zb  = (ushort_t*)(w + off);  off += (size_t)N_ESLOT * 384 * 2;       // 25.2 MB
    int* cnt  = (int*)(w + off);  off += (size_t)(NKEY + 1) * 4 + 252; off &= ~(size_t)255;
    int* rank = (int*)(w + off);  off += (size_t)NE * 4;
    int* eidx = (int*)(w + off);  off += (size_t)(NE + 64) * 4;

    const ushort_t* W1pack = pack;
    const ushort_t* W2pack = pack + (size_t)1536 * 8;
    const ushort_t* HWT    = pack + (size_t)(1536 + 3072) * 8;
    const ushort_t* GT     = pack + (size_t)(1536 + 3072 + 4096) * 8;

    hipMemsetAsync(cnt, 0, (size_t)(NKEY + 1) * 4, stream);
    hipMemsetAsync(eidx, 0xFF, (size_t)(NE + 64) * 4, stream);   // -1 pads

    prep_kernel<<<86, 256, 0, stream>>>(
        w_n_W1, w_same_W1, w_anti_W1, w_n_W2, w_same_W2, w_anti_W2,
        h_W, g_n_W, g_same_W, g_anti_W,
        w_n_b1, w_same_b1, w_anti_b1, w_n_b2, w_same_b2, w_anti_b2,
        g_n_b, g_same_b, g_anti_b,
        (ushort_t*)pack, b1cat, b2cat, gbsum);

    hx_nuc_perm<<<512, 256, 0, stream>>>(nuc, hxb);
    hx_elec_mfma<<<N_ESLOT / 64, 256, 0, stream>>>(elec, HWT, h_b, hxb);

    hist_kernel<<<NE / 256, 256, 0, stream>>>(receivers, e_type, cnt, rank);
    scan_local<<<NSB, 256, 0, stream>>>(cnt, bsum);
    scan_bsum<<<1, 128, 0, stream>>>(bsum, seg, cnt);
    scatter_kernel<<<NE / 256, 256, 0, stream>>>(receivers, e_type, cnt, bsum, rank, eidx);

    edge_fused<<<1024, 256, 0, stream>>>(dist, senders, eidx, seg,
        (const bf16x8*)W1pack, b1cat, (const bf16x8*)W2pack, b2cat, hxb, buf);

    zgather2<<<2048, 256, 0, stream>>>(cnt, bsum, buf, Zb);

    gout_mfma<<<N_ESLOT / 64, 512, 0, stream>>>(Zb, elec, GT, gbsum, out);
}